// Round 1
// baseline (893.483 us; speedup 1.0000x reference)
//
#include <hip/hip_runtime.h>

#define EPSF 1e-5f

// ---------------- workspace layout (float offsets) ----------------
// stats region (partial sums + scale/shift), then big reused buffers
#define P1S 0          // [20][4096]
#define P1Q 81920
#define P2S 163840     // [40][1024]
#define P2Q 204800
#define P3S 245760     // [60][256]
#define P3Q 261120
#define P4S 276480     // [80][36]
#define P4Q 279360
#define SC1 282240
#define SH1 282260
#define SC2 282280
#define SH2 282320
#define SC3 282360
#define SH3 282420
#define SC4 282480
#define SH4 282560
#define SC5 282640     // [768]
#define SH5 283408

#define OFF_A 524288            // 19,681,280 cap (conv1raw/conv2raw/conv3raw/lcraw)
#define OFF_B 20205568          // 4,920,320 cap (pool1/pool2)
#define OFF_C 25125888          // h: 752,640
#define OFF_D 25878528          // x2: 737,280
#define OFF_Y 26615808          // y: 196,608

// ---------------- helpers ----------------
__device__ __forceinline__ void blockReduce2(float& v1, float& v2) {
  #pragma unroll
  for (int off = 32; off > 0; off >>= 1) {
    v1 += __shfl_down(v1, off);
    v2 += __shfl_down(v2, off);
  }
  __shared__ float s1[4], s2[4];
  const int wid = threadIdx.x >> 6, lane = threadIdx.x & 63;
  if (lane == 0) { s1[wid] = v1; s2[wid] = v2; }
  __syncthreads();
  if (threadIdx.x == 0) { v1 = s1[0]+s1[1]+s1[2]+s1[3]; v2 = s2[0]+s2[1]+s2[2]+s2[3]; }
}

// ---------------- conv kernels (raw out + per-block partial sums) ----------------
__global__ __launch_bounds__(256) void conv1_kernel(
    const float* __restrict__ x, const float* __restrict__ w, const float* __restrict__ cb,
    float* __restrict__ out, float* __restrict__ ps, float* __restrict__ pq) {
  const int sp = blockIdx.x * 256 + threadIdx.x;
  const int c = blockIdx.y, b = blockIdx.z;
  __shared__ float wsh[27];
  if (threadIdx.x < 27) wsh[threadIdx.x] = w[c * 27 + threadIdx.x];
  __syncthreads();
  float val = 0.f;
  if (sp < 3844) {
    const int oy = sp / 62, ox = sp - oy * 62;
    const float* xb = x + (size_t)b * 3 * 4096 + oy * 64 + ox;
    float acc = cb[c];
    #pragma unroll
    for (int ic = 0; ic < 3; ic++)
      #pragma unroll
      for (int ky = 0; ky < 3; ky++)
        #pragma unroll
        for (int kx = 0; kx < 3; kx++)
          acc = fmaf(xb[ic * 4096 + ky * 64 + kx], wsh[(ic * 3 + ky) * 3 + kx], acc);
    out[(size_t)(b * 20 + c) * 3844 + sp] = acc;
    val = acc;
  }
  float v2 = val * val;
  blockReduce2(val, v2);
  if (threadIdx.x == 0) {
    ps[c * 4096 + blockIdx.z * 16 + blockIdx.x] = val;
    pq[c * 4096 + blockIdx.z * 16 + blockIdx.x] = v2;
  }
}

__global__ __launch_bounds__(256) void conv2_kernel(
    const float* __restrict__ in, const float* __restrict__ w, const float* __restrict__ cb,
    float* __restrict__ out, float* __restrict__ ps, float* __restrict__ pq) {
  const int sp = blockIdx.x * 256 + threadIdx.x;
  const int c = blockIdx.y, b = blockIdx.z;
  __shared__ float wsh[80];
  if (threadIdx.x < 80) wsh[threadIdx.x] = w[c * 80 + threadIdx.x];
  __syncthreads();
  float val = 0.f;
  if (sp < 900) {
    const int oy = sp / 30, ox = sp - oy * 30;
    const float* ib = in + (size_t)b * 20 * 961 + oy * 31 + ox;
    float acc = cb[c];
    #pragma unroll 5
    for (int ic = 0; ic < 20; ic++) {
      acc = fmaf(ib[ic * 961],      wsh[ic * 4 + 0], acc);
      acc = fmaf(ib[ic * 961 + 1],  wsh[ic * 4 + 1], acc);
      acc = fmaf(ib[ic * 961 + 31], wsh[ic * 4 + 2], acc);
      acc = fmaf(ib[ic * 961 + 32], wsh[ic * 4 + 3], acc);
    }
    out[(size_t)(b * 40 + c) * 900 + sp] = acc;
    val = acc;
  }
  float v2 = val * val;
  blockReduce2(val, v2);
  if (threadIdx.x == 0) {
    ps[c * 1024 + blockIdx.z * 4 + blockIdx.x] = val;
    pq[c * 1024 + blockIdx.z * 4 + blockIdx.x] = v2;
  }
}

__global__ __launch_bounds__(256) void conv3_kernel(
    const float* __restrict__ in, const float* __restrict__ w, const float* __restrict__ cb,
    float* __restrict__ out, float* __restrict__ ps, float* __restrict__ pq) {
  const int sp = threadIdx.x;
  const int c = blockIdx.y, b = blockIdx.z;
  __shared__ float wsh[160];
  if (threadIdx.x < 160) wsh[threadIdx.x] = w[c * 160 + threadIdx.x];
  __syncthreads();
  float val = 0.f;
  if (sp < 196) {
    const int oy = sp / 14, ox = sp - oy * 14;
    const float* ib = in + (size_t)b * 40 * 225 + oy * 15 + ox;
    float acc = cb[c];
    #pragma unroll 8
    for (int ic = 0; ic < 40; ic++) {
      acc = fmaf(ib[ic * 225],      wsh[ic * 4 + 0], acc);
      acc = fmaf(ib[ic * 225 + 1],  wsh[ic * 4 + 1], acc);
      acc = fmaf(ib[ic * 225 + 15], wsh[ic * 4 + 2], acc);
      acc = fmaf(ib[ic * 225 + 16], wsh[ic * 4 + 3], acc);
    }
    out[(size_t)(b * 60 + c) * 196 + sp] = acc;
    val = acc;
  }
  float v2 = val * val;
  blockReduce2(val, v2);
  if (threadIdx.x == 0) {
    ps[c * 256 + blockIdx.z] = val;
    pq[c * 256 + blockIdx.z] = v2;
  }
}

// ---------------- BN finalize: partials -> scale/shift ----------------
template<int SLOTS>
__global__ __launch_bounds__(256) void bnfin_kernel(
    const float* __restrict__ ps, const float* __restrict__ pq,
    const float* __restrict__ g, const float* __restrict__ bet,
    float* __restrict__ scale, float* __restrict__ shift, float invN) {
  const int c = blockIdx.x;
  float s = 0.f, q = 0.f;
  for (int i = threadIdx.x; i < SLOTS; i += 256) { s += ps[c * SLOTS + i]; q += pq[c * SLOTS + i]; }
  blockReduce2(s, q);
  if (threadIdx.x == 0) {
    const float m = s * invN;
    const float var = q * invN - m * m;
    const float sc = g[c] * rsqrtf(var + EPSF);
    scale[c] = sc;
    shift[c] = bet[c] - m * sc;
  }
}

// ---------------- fused BN + ReLU + 2x2 maxpool ----------------
template<int C, int Hin, int Win, int Hout, int Wout>
__global__ __launch_bounds__(256) void bnrelupool_kernel(
    const float* __restrict__ in, float* __restrict__ out,
    const float* __restrict__ scale, const float* __restrict__ shift, int total) {
  const int idx = blockIdx.x * 256 + threadIdx.x;
  if (idx >= total) return;
  const int px = idx % Wout;
  int t = idx / Wout;
  const int py = t % Hout; t /= Hout;
  const int c = t % C;
  const int b = t / C;
  const float sc = scale[c], sh = shift[c];
  const float* p = in + ((size_t)(b * C + c) * Hin + 2 * py) * Win + 2 * px;
  float a0 = fmaxf(fmaf(p[0], sc, sh), 0.f);
  float a1 = fmaxf(fmaf(p[1], sc, sh), 0.f);
  float a2 = fmaxf(fmaf(p[Win], sc, sh), 0.f);
  float a3 = fmaxf(fmaf(p[Win + 1], sc, sh), 0.f);
  out[idx] = fmaxf(fmaxf(a0, a1), fmaxf(a2, a3));
}

// ---------------- LocallyConnected2d ----------------
__global__ __launch_bounds__(256) void lc_kernel(
    const float* __restrict__ h, const float* __restrict__ w, const float* __restrict__ lb,
    float* __restrict__ out, float* __restrict__ ps, float* __restrict__ pq) {
  const int o = blockIdx.x / 36, sp = blockIdx.x - o * 36;
  const int i = sp / 6, j = sp - i * 6;
  const int b = threadIdx.x;
  __shared__ float wsh[240];
  if (threadIdx.x < 240) {
    const int c = threadIdx.x >> 2, k = threadIdx.x & 3;
    wsh[threadIdx.x] = w[((size_t)(o * 60 + c) * 36 + sp) * 4 + k];
  }
  __syncthreads();
  const float* hb = h + (size_t)b * 2940 + i * 7 + j;
  float acc = lb[o * 36 + sp];
  #pragma unroll 4
  for (int c = 0; c < 60; c++) {
    acc = fmaf(hb[c * 49],     wsh[c * 4 + 0], acc);
    acc = fmaf(hb[c * 49 + 1], wsh[c * 4 + 1], acc);
    acc = fmaf(hb[c * 49 + 7], wsh[c * 4 + 2], acc);
    acc = fmaf(hb[c * 49 + 8], wsh[c * 4 + 3], acc);
  }
  out[(size_t)(b * 80 + o) * 36 + sp] = acc;
  float v2 = acc * acc, v1 = acc;
  blockReduce2(v1, v2);
  if (threadIdx.x == 0) { ps[o * 36 + sp] = v1; pq[o * 36 + sp] = v2; }
}

__global__ __launch_bounds__(256) void lcpost_kernel(
    const float* __restrict__ in, float* __restrict__ out,
    const float* __restrict__ scale, const float* __restrict__ shift) {
  const int idx = blockIdx.x * 256 + threadIdx.x;  // 737280 exact
  const int o = (idx / 36) % 80;
  out[idx] = fmaxf(fmaf(in[idx], scale[o], shift[o]), 0.f);
}

// ---------------- FC GEMM: [256,5820] x [768,5820]^T, split-K atomics ----------------
__global__ __launch_bounds__(256) void fc_gemm_kernel(
    const float* __restrict__ h, const float* __restrict__ x2,
    const float* __restrict__ W, float* __restrict__ Y) {
  const int m0 = blockIdx.x * 64;
  const int n0 = blockIdx.y * 64;
  const int tid = threadIdx.x;
  const int tx = tid & 15, ty = tid >> 4;
  __shared__ float As[16][68];
  __shared__ float Ws[16][68];
  float acc[4][4] = {};
  const int kbeg = blockIdx.z * 736;
  const int kend = (kbeg + 736 < 5820) ? (kbeg + 736) : 5820;
  for (int k0 = kbeg; k0 < kend; k0 += 16) {
    #pragma unroll
    for (int l = 0; l < 4; l++) {
      const int e = tid + l * 256;
      const int r = e >> 4, kk = e & 15;
      const int k = k0 + kk;
      float av = 0.f, wv = 0.f;
      if (k < 5820) {
        const int mb = m0 + r;
        av = (k < 2940) ? h[mb * 2940 + k] : x2[mb * 2880 + (k - 2940)];
        wv = W[(size_t)(n0 + r) * 5820 + k];
      }
      As[kk][r] = av;
      Ws[kk][r] = wv;
    }
    __syncthreads();
    #pragma unroll
    for (int kk = 0; kk < 16; kk++) {
      const float4 a4 = *(const float4*)&As[kk][ty * 4];
      const float4 b4 = *(const float4*)&Ws[kk][tx * 4];
      const float a[4] = {a4.x, a4.y, a4.z, a4.w};
      const float bb[4] = {b4.x, b4.y, b4.z, b4.w};
      #pragma unroll
      for (int ii = 0; ii < 4; ii++)
        #pragma unroll
        for (int jj = 0; jj < 4; jj++)
          acc[ii][jj] = fmaf(a[ii], bb[jj], acc[ii][jj]);
    }
    __syncthreads();
  }
  #pragma unroll
  for (int ii = 0; ii < 4; ii++)
    #pragma unroll
    for (int jj = 0; jj < 4; jj++)
      atomicAdd(&Y[(size_t)(m0 + ty * 4 + ii) * 768 + (n0 + tx * 4 + jj)], acc[ii][jj]);
}

// ---------------- BN5 stats (per-feature over batch) ----------------
__global__ __launch_bounds__(256) void bn5_stats_kernel(
    const float* __restrict__ Y, const float* __restrict__ g, const float* __restrict__ bet,
    float* __restrict__ scale, float* __restrict__ shift) {
  const int n = blockIdx.x;
  const float v = Y[(size_t)threadIdx.x * 768 + n];
  float s = v, q = v * v;
  blockReduce2(s, q);
  if (threadIdx.x == 0) {
    const float m = s * (1.f / 256.f);
    const float var = q * (1.f / 256.f) - m * m;
    const float sc = g[n] * rsqrtf(var + EPSF);
    scale[n] = sc;
    shift[n] = bet[n] - m * sc;
  }
}

// ---------------- final fuse ----------------
__global__ __launch_bounds__(256) void final_kernel(
    const float* __restrict__ Y, const float* __restrict__ scale, const float* __restrict__ shift,
    const float* __restrict__ fw, const float* __restrict__ fb, float* __restrict__ out) {
  const int idx = blockIdx.x * 256 + threadIdx.x;  // 12288 exact
  const int b = idx / 48, hh = idx - b * 48;
  const float* yb = Y + (size_t)b * 768 + hh * 16;
  const float* sc = scale + hh * 16;
  const float* sh = shift + hh * 16;
  const float* w = fw + hh * 16;
  float acc = fb[hh];
  #pragma unroll
  for (int s = 0; s < 16; s++)
    acc += fmaxf(fmaf(yb[s], sc[s], sh[s]), 0.f) * w[s];
  out[idx] = acc;
}

// ---------------- launch ----------------
extern "C" void kernel_launch(void* const* d_in, const int* in_sizes, int n_in,
                              void* d_out, int out_size, void* d_ws, size_t ws_size,
                              hipStream_t stream) {
  const float* x   = (const float*)d_in[0];
  const float* c1w = (const float*)d_in[1];
  const float* c1b = (const float*)d_in[2];
  const float* g1  = (const float*)d_in[3];
  const float* b1  = (const float*)d_in[4];
  const float* c2w = (const float*)d_in[5];
  const float* c2b = (const float*)d_in[6];
  const float* g2  = (const float*)d_in[7];
  const float* b2  = (const float*)d_in[8];
  const float* c3w = (const float*)d_in[9];
  const float* c3b = (const float*)d_in[10];
  const float* g3  = (const float*)d_in[11];
  const float* b3  = (const float*)d_in[12];
  const float* lcw = (const float*)d_in[13];
  const float* lcb = (const float*)d_in[14];
  const float* g4  = (const float*)d_in[15];
  const float* b4  = (const float*)d_in[16];
  const float* fcw = (const float*)d_in[17];
  const float* g5  = (const float*)d_in[19];
  const float* b5  = (const float*)d_in[20];
  const float* fw  = (const float*)d_in[21];
  const float* fb  = (const float*)d_in[22];

  float* ws = (float*)d_ws;
  float* A  = ws + OFF_A;
  float* B_ = ws + OFF_B;
  float* C_ = ws + OFF_C;
  float* D_ = ws + OFF_D;
  float* Y  = ws + OFF_Y;

  // zero the GEMM accumulator (ws is poisoned 0xAA before each launch)
  hipMemsetAsync(Y, 0, 196608 * sizeof(float), stream);

  // stage 1
  conv1_kernel<<<dim3(16, 20, 256), 256, 0, stream>>>(x, c1w, c1b, A, ws + P1S, ws + P1Q);
  bnfin_kernel<4096><<<20, 256, 0, stream>>>(ws + P1S, ws + P1Q, g1, b1, ws + SC1, ws + SH1, 1.f / 984064.f);
  bnrelupool_kernel<20, 62, 62, 31, 31><<<19220, 256, 0, stream>>>(A, B_, ws + SC1, ws + SH1, 4920320);
  // stage 2
  conv2_kernel<<<dim3(4, 40, 256), 256, 0, stream>>>(B_, c2w, c2b, A, ws + P2S, ws + P2Q);
  bnfin_kernel<1024><<<40, 256, 0, stream>>>(ws + P2S, ws + P2Q, g2, b2, ws + SC2, ws + SH2, 1.f / 230400.f);
  bnrelupool_kernel<40, 30, 30, 15, 15><<<9000, 256, 0, stream>>>(A, B_, ws + SC2, ws + SH2, 2304000);
  // stage 3
  conv3_kernel<<<dim3(1, 60, 256), 256, 0, stream>>>(B_, c3w, c3b, A, ws + P3S, ws + P3Q);
  bnfin_kernel<256><<<60, 256, 0, stream>>>(ws + P3S, ws + P3Q, g3, b3, ws + SC3, ws + SH3, 1.f / 50176.f);
  bnrelupool_kernel<60, 14, 14, 7, 7><<<2940, 256, 0, stream>>>(A, C_, ws + SC3, ws + SH3, 752640);
  // locally connected
  lc_kernel<<<2880, 256, 0, stream>>>(C_, lcw, lcb, A, ws + P4S, ws + P4Q);
  bnfin_kernel<36><<<80, 256, 0, stream>>>(ws + P4S, ws + P4Q, g4, b4, ws + SC4, ws + SH4, 1.f / 9216.f);
  lcpost_kernel<<<2880, 256, 0, stream>>>(A, D_, ws + SC4, ws + SH4);
  // fc (fc_b cancels under BN1d)
  fc_gemm_kernel<<<dim3(4, 12, 8), 256, 0, stream>>>(C_, D_, fcw, Y);
  bn5_stats_kernel<<<768, 256, 0, stream>>>(Y, g5, b5, ws + SC5, ws + SH5);
  final_kernel<<<48, 256, 0, stream>>>(Y, ws + SC5, ws + SH5, fw, fb, (float*)d_out);
}

// Round 2
// 727.401 us; speedup vs baseline: 1.2283x; 1.2283x over previous
//
#include <hip/hip_runtime.h>

#define EPSF 1e-5f

// ---------------- workspace layout (float offsets) ----------------
#define P1S 0          // [20][4096]
#define P1Q 81920
#define P2S 163840     // [40][1024]
#define P2Q 204800
#define P3S 245760     // [60][256]
#define P3Q 261120
#define P4S 276480     // [80][36]
#define P4Q 279360
#define SC1 282240
#define SH1 282260
#define SC2 282280
#define SH2 282320
#define SC3 282360
#define SH3 282420
#define SC4 282480
#define SH4 282560
#define SC5 282640     // [768]
#define SH5 283408

#define OFF_A 524288            // conv1raw/conv2raw/conv3raw/lcrawT (19.6M cap)
#define OFF_B 20205568          // pool1/pool2/hT (4.9M cap)
#define OFF_C 25125888          // h (x1): 752,640
#define OFF_D 25878528          // x2: 737,280
#define OFF_Y 26615808          // y: 196,608

// ---------------- helpers ----------------
__device__ __forceinline__ void blockReduce2(float& v1, float& v2) {
  __syncthreads();  // safe for repeated calls (shared buffer reuse)
  #pragma unroll
  for (int off = 32; off > 0; off >>= 1) {
    v1 += __shfl_down(v1, off);
    v2 += __shfl_down(v2, off);
  }
  __shared__ float s1[4], s2[4];
  const int wid = threadIdx.x >> 6, lane = threadIdx.x & 63;
  if (lane == 0) { s1[wid] = v1; s2[wid] = v2; }
  __syncthreads();
  if (threadIdx.x == 0) { v1 = s1[0]+s1[1]+s1[2]+s1[3]; v2 = s2[0]+s2[1]+s2[2]+s2[3]; }
}

// ---------------- conv kernels (raw out + per-block partial sums) ----------------
__global__ __launch_bounds__(256) void conv1_kernel(
    const float* __restrict__ x, const float* __restrict__ w, const float* __restrict__ cb,
    float* __restrict__ out, float* __restrict__ ps, float* __restrict__ pq) {
  const int sp = blockIdx.x * 256 + threadIdx.x;
  const int c = blockIdx.y, b = blockIdx.z;
  __shared__ float wsh[27];
  if (threadIdx.x < 27) wsh[threadIdx.x] = w[c * 27 + threadIdx.x];
  __syncthreads();
  float val = 0.f;
  if (sp < 3844) {
    const int oy = sp / 62, ox = sp - oy * 62;
    const float* xb = x + (size_t)b * 3 * 4096 + oy * 64 + ox;
    float acc = cb[c];
    #pragma unroll
    for (int ic = 0; ic < 3; ic++)
      #pragma unroll
      for (int ky = 0; ky < 3; ky++)
        #pragma unroll
        for (int kx = 0; kx < 3; kx++)
          acc = fmaf(xb[ic * 4096 + ky * 64 + kx], wsh[(ic * 3 + ky) * 3 + kx], acc);
    out[(size_t)(b * 20 + c) * 3844 + sp] = acc;
    val = acc;
  }
  float v2 = val * val;
  blockReduce2(val, v2);
  if (threadIdx.x == 0) {
    ps[c * 4096 + blockIdx.z * 16 + blockIdx.x] = val;
    pq[c * 4096 + blockIdx.z * 16 + blockIdx.x] = v2;
  }
}

__global__ __launch_bounds__(256) void conv2_kernel(
    const float* __restrict__ in, const float* __restrict__ w, const float* __restrict__ cb,
    float* __restrict__ out, float* __restrict__ ps, float* __restrict__ pq) {
  const int sp = blockIdx.x * 256 + threadIdx.x;
  const int c = blockIdx.y, b = blockIdx.z;
  __shared__ float wsh[80];
  if (threadIdx.x < 80) wsh[threadIdx.x] = w[c * 80 + threadIdx.x];
  __syncthreads();
  float val = 0.f;
  if (sp < 900) {
    const int oy = sp / 30, ox = sp - oy * 30;
    const float* ib = in + (size_t)b * 20 * 961 + oy * 31 + ox;
    float acc = cb[c];
    #pragma unroll 5
    for (int ic = 0; ic < 20; ic++) {
      acc = fmaf(ib[ic * 961],      wsh[ic * 4 + 0], acc);
      acc = fmaf(ib[ic * 961 + 1],  wsh[ic * 4 + 1], acc);
      acc = fmaf(ib[ic * 961 + 31], wsh[ic * 4 + 2], acc);
      acc = fmaf(ib[ic * 961 + 32], wsh[ic * 4 + 3], acc);
    }
    out[(size_t)(b * 40 + c) * 900 + sp] = acc;
    val = acc;
  }
  float v2 = val * val;
  blockReduce2(val, v2);
  if (threadIdx.x == 0) {
    ps[c * 1024 + blockIdx.z * 4 + blockIdx.x] = val;
    pq[c * 1024 + blockIdx.z * 4 + blockIdx.x] = v2;
  }
}

__global__ __launch_bounds__(256) void conv3_kernel(
    const float* __restrict__ in, const float* __restrict__ w, const float* __restrict__ cb,
    float* __restrict__ out, float* __restrict__ ps, float* __restrict__ pq) {
  const int sp = threadIdx.x;
  const int c = blockIdx.y, b = blockIdx.z;
  __shared__ float wsh[160];
  if (threadIdx.x < 160) wsh[threadIdx.x] = w[c * 160 + threadIdx.x];
  __syncthreads();
  float val = 0.f;
  if (sp < 196) {
    const int oy = sp / 14, ox = sp - oy * 14;
    const float* ib = in + (size_t)b * 40 * 225 + oy * 15 + ox;
    float acc = cb[c];
    #pragma unroll 8
    for (int ic = 0; ic < 40; ic++) {
      acc = fmaf(ib[ic * 225],      wsh[ic * 4 + 0], acc);
      acc = fmaf(ib[ic * 225 + 1],  wsh[ic * 4 + 1], acc);
      acc = fmaf(ib[ic * 225 + 15], wsh[ic * 4 + 2], acc);
      acc = fmaf(ib[ic * 225 + 16], wsh[ic * 4 + 3], acc);
    }
    out[(size_t)(b * 60 + c) * 196 + sp] = acc;
    val = acc;
  }
  float v2 = val * val;
  blockReduce2(val, v2);
  if (threadIdx.x == 0) {
    ps[c * 256 + blockIdx.z] = val;
    pq[c * 256 + blockIdx.z] = v2;
  }
}

// ---------------- BN finalize: partials -> scale/shift ----------------
template<int SLOTS>
__global__ __launch_bounds__(256) void bnfin_kernel(
    const float* __restrict__ ps, const float* __restrict__ pq,
    const float* __restrict__ g, const float* __restrict__ bet,
    float* __restrict__ scale, float* __restrict__ shift, float invN) {
  const int c = blockIdx.x;
  float s = 0.f, q = 0.f;
  for (int i = threadIdx.x; i < SLOTS; i += 256) { s += ps[c * SLOTS + i]; q += pq[c * SLOTS + i]; }
  blockReduce2(s, q);
  if (threadIdx.x == 0) {
    const float m = s * invN;
    const float var = q * invN - m * m;
    const float sc = g[c] * rsqrtf(var + EPSF);
    scale[c] = sc;
    shift[c] = bet[c] - m * sc;
  }
}

// ---------------- fused BN + ReLU + 2x2 maxpool ----------------
template<int C, int Hin, int Win, int Hout, int Wout>
__global__ __launch_bounds__(256) void bnrelupool_kernel(
    const float* __restrict__ in, float* __restrict__ out,
    const float* __restrict__ scale, const float* __restrict__ shift, int total) {
  const int idx = blockIdx.x * 256 + threadIdx.x;
  if (idx >= total) return;
  const int px = idx % Wout;
  int t = idx / Wout;
  const int py = t % Hout; t /= Hout;
  const int c = t % C;
  const int b = t / C;
  const float sc = scale[c], sh = shift[c];
  const float* p = in + ((size_t)(b * C + c) * Hin + 2 * py) * Win + 2 * px;
  float a0 = fmaxf(fmaf(p[0], sc, sh), 0.f);
  float a1 = fmaxf(fmaf(p[1], sc, sh), 0.f);
  float a2 = fmaxf(fmaf(p[Win], sc, sh), 0.f);
  float a3 = fmaxf(fmaf(p[Win + 1], sc, sh), 0.f);
  out[idx] = fmaxf(fmaxf(a0, a1), fmaxf(a2, a3));
}

// ---------------- transpose h [256][2940] -> hT [2940][256] ----------------
__global__ __launch_bounds__(256) void transpose_h_kernel(
    const float* __restrict__ in, float* __restrict__ out) {
  __shared__ float tile[64][65];
  const int lx = threadIdx.x & 63, ly = threadIdx.x >> 6;
  const int c0 = blockIdx.x * 64;   // cp dim (2940)
  const int r0 = blockIdx.y * 64;   // b dim (256)
  #pragma unroll
  for (int i = 0; i < 16; i++) {
    const int b = r0 + ly + i * 4;
    const int cp = c0 + lx;
    tile[ly + i * 4][lx] = (cp < 2940) ? in[(size_t)b * 2940 + cp] : 0.f;
  }
  __syncthreads();
  #pragma unroll
  for (int i = 0; i < 16; i++) {
    const int cp = c0 + ly + i * 4;
    if (cp < 2940) out[(size_t)cp * 256 + r0 + lx] = tile[lx][ly + i * 4];
  }
}

// ---------------- LocallyConnected2d v2 (coalesced, o-tiled) ----------------
// grid (36 sp, 10 o-tiles), 256 threads = batch. hT [2940][256], out lcT [2880][256]
__global__ __launch_bounds__(256) void lc2_kernel(
    const float* __restrict__ hT, const float* __restrict__ w, const float* __restrict__ lb,
    float* __restrict__ outT, float* __restrict__ ps, float* __restrict__ pq) {
  const int sp = blockIdx.x;
  const int o0 = blockIdx.y * 8;
  const int b = threadIdx.x;
  __shared__ float wsh[8 * 240];
  for (int e = threadIdx.x; e < 1920; e += 256) {
    const int ol = e / 240, ck = e - ol * 240;
    const int c = ck >> 2, k = ck & 3;
    wsh[e] = w[((size_t)((o0 + ol) * 60 + c) * 36 + sp) * 4 + k];
  }
  __syncthreads();
  const int i = sp / 6, j = sp - i * 6;
  const int pos0 = i * 7 + j;
  float acc[8] = {};
  #pragma unroll 4
  for (int c = 0; c < 60; c++) {
    const float h0 = hT[(size_t)(c * 49 + pos0) * 256 + b];
    const float h1 = hT[(size_t)(c * 49 + pos0 + 1) * 256 + b];
    const float h2 = hT[(size_t)(c * 49 + pos0 + 7) * 256 + b];
    const float h3 = hT[(size_t)(c * 49 + pos0 + 8) * 256 + b];
    #pragma unroll
    for (int ol = 0; ol < 8; ol++) {
      const float* wp = &wsh[ol * 240 + c * 4];
      acc[ol] = fmaf(h0, wp[0], acc[ol]);
      acc[ol] = fmaf(h1, wp[1], acc[ol]);
      acc[ol] = fmaf(h2, wp[2], acc[ol]);
      acc[ol] = fmaf(h3, wp[3], acc[ol]);
    }
  }
  #pragma unroll
  for (int ol = 0; ol < 8; ol++) {
    const int o = o0 + ol;
    const float val = acc[ol] + lb[o * 36 + sp];
    outT[(size_t)(o * 36 + sp) * 256 + b] = val;
    float v1 = val, v2 = val * val;
    blockReduce2(v1, v2);
    if (threadIdx.x == 0) { ps[o * 36 + sp] = v1; pq[o * 36 + sp] = v2; }
  }
}

// ---------------- lcpost: BN+ReLU + transpose lcT [2880][256] -> x2 [256][2880] ----
__global__ __launch_bounds__(256) void lcpost2_kernel(
    const float* __restrict__ inT, float* __restrict__ out,
    const float* __restrict__ scale, const float* __restrict__ shift) {
  __shared__ float tile[64][65];
  const int lx = threadIdx.x & 63, ly = threadIdx.x >> 6;
  const int k0 = blockIdx.x * 64;   // k dim (2880)
  const int b0 = blockIdx.y * 64;   // b dim (256)
  #pragma unroll
  for (int i = 0; i < 16; i++) {
    const int k = k0 + ly + i * 4;
    const int o = k / 36;
    const float v = inT[(size_t)k * 256 + b0 + lx];
    tile[ly + i * 4][lx] = fmaxf(fmaf(v, scale[o], shift[o]), 0.f);
  }
  __syncthreads();
  #pragma unroll
  for (int i = 0; i < 16; i++) {
    const int b = b0 + ly + i * 4;
    out[(size_t)b * 2880 + k0 + lx] = tile[lx][ly + i * 4];
  }
}

// ---------------- FC GEMM: [256,5820] x [768,5820]^T, split-K atomics ----------------
__global__ __launch_bounds__(256) void fc_gemm_kernel(
    const float* __restrict__ h, const float* __restrict__ x2,
    const float* __restrict__ W, float* __restrict__ Y) {
  const int m0 = blockIdx.x * 64;
  const int n0 = blockIdx.y * 64;
  const int tid = threadIdx.x;
  const int tx = tid & 15, ty = tid >> 4;
  __shared__ float As[16][68];
  __shared__ float Ws[16][68];
  float acc[4][4] = {};
  const int kbeg = blockIdx.z * 736;
  const int kend = (kbeg + 736 < 5820) ? (kbeg + 736) : 5820;
  for (int k0 = kbeg; k0 < kend; k0 += 16) {
    #pragma unroll
    for (int l = 0; l < 4; l++) {
      const int e = tid + l * 256;
      const int r = e >> 4, kk = e & 15;
      const int k = k0 + kk;
      float av = 0.f, wv = 0.f;
      if (k < 5820) {
        const int mb = m0 + r;
        av = (k < 2940) ? h[mb * 2940 + k] : x2[mb * 2880 + (k - 2940)];
        wv = W[(size_t)(n0 + r) * 5820 + k];
      }
      As[kk][r] = av;
      Ws[kk][r] = wv;
    }
    __syncthreads();
    #pragma unroll
    for (int kk = 0; kk < 16; kk++) {
      const float4 a4 = *(const float4*)&As[kk][ty * 4];
      const float4 b4 = *(const float4*)&Ws[kk][tx * 4];
      const float a[4] = {a4.x, a4.y, a4.z, a4.w};
      const float bb[4] = {b4.x, b4.y, b4.z, b4.w};
      #pragma unroll
      for (int ii = 0; ii < 4; ii++)
        #pragma unroll
        for (int jj = 0; jj < 4; jj++)
          acc[ii][jj] = fmaf(a[ii], bb[jj], acc[ii][jj]);
    }
    __syncthreads();
  }
  #pragma unroll
  for (int ii = 0; ii < 4; ii++)
    #pragma unroll
    for (int jj = 0; jj < 4; jj++)
      atomicAdd(&Y[(size_t)(m0 + ty * 4 + ii) * 768 + (n0 + tx * 4 + jj)], acc[ii][jj]);
}

// ---------------- BN5 stats (per-feature over batch), coalesced ----------------
__global__ __launch_bounds__(256) void bn5_stats_kernel(
    const float* __restrict__ Y, const float* __restrict__ g, const float* __restrict__ bet,
    float* __restrict__ scale, float* __restrict__ shift) {
  const int tx = threadIdx.x & 63, ty = threadIdx.x >> 6;
  const int n = blockIdx.x * 64 + tx;
  float s = 0.f, q = 0.f;
  for (int bi = 0; bi < 64; bi++) {
    const float v = Y[(size_t)(bi * 4 + ty) * 768 + n];
    s += v; q += v * v;
  }
  __shared__ float rs[4][64], rq[4][64];
  rs[ty][tx] = s; rq[ty][tx] = q;
  __syncthreads();
  if (ty == 0) {
    s = rs[0][tx] + rs[1][tx] + rs[2][tx] + rs[3][tx];
    q = rq[0][tx] + rq[1][tx] + rq[2][tx] + rq[3][tx];
    const float m = s * (1.f / 256.f);
    const float var = q * (1.f / 256.f) - m * m;
    const float sc = g[n] * rsqrtf(var + EPSF);
    scale[n] = sc;
    shift[n] = bet[n] - m * sc;
  }
}

// ---------------- final fuse ----------------
__global__ __launch_bounds__(256) void final_kernel(
    const float* __restrict__ Y, const float* __restrict__ scale, const float* __restrict__ shift,
    const float* __restrict__ fw, const float* __restrict__ fb, float* __restrict__ out) {
  const int idx = blockIdx.x * 256 + threadIdx.x;  // 12288 exact
  const int b = idx / 48, hh = idx - b * 48;
  const float* yb = Y + (size_t)b * 768 + hh * 16;
  const float* sc = scale + hh * 16;
  const float* sh = shift + hh * 16;
  const float* w = fw + hh * 16;
  float acc = fb[hh];
  #pragma unroll
  for (int s = 0; s < 16; s++)
    acc += fmaxf(fmaf(yb[s], sc[s], sh[s]), 0.f) * w[s];
  out[idx] = acc;
}

// ---------------- launch ----------------
extern "C" void kernel_launch(void* const* d_in, const int* in_sizes, int n_in,
                              void* d_out, int out_size, void* d_ws, size_t ws_size,
                              hipStream_t stream) {
  const float* x   = (const float*)d_in[0];
  const float* c1w = (const float*)d_in[1];
  const float* c1b = (const float*)d_in[2];
  const float* g1  = (const float*)d_in[3];
  const float* b1  = (const float*)d_in[4];
  const float* c2w = (const float*)d_in[5];
  const float* c2b = (const float*)d_in[6];
  const float* g2  = (const float*)d_in[7];
  const float* b2  = (const float*)d_in[8];
  const float* c3w = (const float*)d_in[9];
  const float* c3b = (const float*)d_in[10];
  const float* g3  = (const float*)d_in[11];
  const float* b3  = (const float*)d_in[12];
  const float* lcw = (const float*)d_in[13];
  const float* lcb = (const float*)d_in[14];
  const float* g4  = (const float*)d_in[15];
  const float* b4  = (const float*)d_in[16];
  const float* fcw = (const float*)d_in[17];
  const float* g5  = (const float*)d_in[19];
  const float* b5  = (const float*)d_in[20];
  const float* fw  = (const float*)d_in[21];
  const float* fb  = (const float*)d_in[22];

  float* ws = (float*)d_ws;
  float* A  = ws + OFF_A;   // conv raw / lcT
  float* B_ = ws + OFF_B;   // pool1/pool2 / hT
  float* C_ = ws + OFF_C;   // h (x1)
  float* D_ = ws + OFF_D;   // x2
  float* Y  = ws + OFF_Y;

  hipMemsetAsync(Y, 0, 196608 * sizeof(float), stream);

  // stage 1
  conv1_kernel<<<dim3(16, 20, 256), 256, 0, stream>>>(x, c1w, c1b, A, ws + P1S, ws + P1Q);
  bnfin_kernel<4096><<<20, 256, 0, stream>>>(ws + P1S, ws + P1Q, g1, b1, ws + SC1, ws + SH1, 1.f / 984064.f);
  bnrelupool_kernel<20, 62, 62, 31, 31><<<19220, 256, 0, stream>>>(A, B_, ws + SC1, ws + SH1, 4920320);
  // stage 2
  conv2_kernel<<<dim3(4, 40, 256), 256, 0, stream>>>(B_, c2w, c2b, A, ws + P2S, ws + P2Q);
  bnfin_kernel<1024><<<40, 256, 0, stream>>>(ws + P2S, ws + P2Q, g2, b2, ws + SC2, ws + SH2, 1.f / 230400.f);
  bnrelupool_kernel<40, 30, 30, 15, 15><<<9000, 256, 0, stream>>>(A, B_, ws + SC2, ws + SH2, 2304000);
  // stage 3
  conv3_kernel<<<dim3(1, 60, 256), 256, 0, stream>>>(B_, c3w, c3b, A, ws + P3S, ws + P3Q);
  bnfin_kernel<256><<<60, 256, 0, stream>>>(ws + P3S, ws + P3Q, g3, b3, ws + SC3, ws + SH3, 1.f / 50176.f);
  bnrelupool_kernel<60, 14, 14, 7, 7><<<2940, 256, 0, stream>>>(A, C_, ws + SC3, ws + SH3, 752640);
  // h -> hT  (B_ free after conv3 consumed it)
  transpose_h_kernel<<<dim3(46, 4), 256, 0, stream>>>(C_, B_);
  // locally connected (coalesced): lcT into A
  lc2_kernel<<<dim3(36, 10), 256, 0, stream>>>(B_, lcw, lcb, A, ws + P4S, ws + P4Q);
  bnfin_kernel<36><<<80, 256, 0, stream>>>(ws + P4S, ws + P4Q, g4, b4, ws + SC4, ws + SH4, 1.f / 9216.f);
  lcpost2_kernel<<<dim3(45, 4), 256, 0, stream>>>(A, D_, ws + SC4, ws + SH4);
  // fc (fc_b cancels under BN1d)
  fc_gemm_kernel<<<dim3(4, 12, 8), 256, 0, stream>>>(C_, D_, fcw, Y);
  bn5_stats_kernel<<<12, 256, 0, stream>>>(Y, g5, b5, ws + SC5, ws + SH5);
  final_kernel<<<48, 256, 0, stream>>>(Y, ws + SC5, ws + SH5, fw, fb, (float*)d_out);
}

// Round 3
// 467.465 us; speedup vs baseline: 1.9113x; 1.5561x over previous
//
#include <hip/hip_runtime.h>

#define EPSF 1e-5f

// ---------------- workspace layout (float offsets) ----------------
#define P1S 0          // [20][4096]
#define P1Q 81920
#define P2S 163840     // [40][1024]
#define P2Q 204800
#define P3S 245760     // [60][256]
#define P3Q 261120
#define P4S 276480     // [80][36]
#define P4Q 279360
#define SC1 282240
#define SH1 282260
#define SC2 282280
#define SH2 282320
#define SC3 282360
#define SH3 282420
#define SC4 282480
#define SH4 282560
#define SC5 282640     // [768]
#define SH5 283408

#define OFF_A 524288            // conv1raw/conv2raw/conv3raw/lcrawT (19.6M cap)
#define OFF_B 20205568          // pool1/pool2/hT (4.9M cap)
#define OFF_C 25125888          // h (x1): 752,640
#define OFF_D 25878528          // x2: 737,280
#define OFF_Y 26615808          // y: 196,608

// ---------------- helpers ----------------
__device__ __forceinline__ void blockReduce2(float& v1, float& v2) {
  __syncthreads();  // protects shared buffer across repeated calls
  #pragma unroll
  for (int off = 32; off > 0; off >>= 1) {
    v1 += __shfl_down(v1, off);
    v2 += __shfl_down(v2, off);
  }
  __shared__ float s1[4], s2[4];
  const int wid = threadIdx.x >> 6, lane = threadIdx.x & 63;
  if (lane == 0) { s1[wid] = v1; s2[wid] = v2; }
  __syncthreads();
  if (threadIdx.x == 0) { v1 = s1[0]+s1[1]+s1[2]+s1[3]; v2 = s2[0]+s2[1]+s2[2]+s2[3]; }
}

// ---------------- conv1: 3x3, ic=3, 20 oc, OCB=5 ----------------
__global__ __launch_bounds__(256) void conv1_kernel(
    const float* __restrict__ x, const float* __restrict__ w, const float* __restrict__ cb,
    float* __restrict__ out, float* __restrict__ ps, float* __restrict__ pq) {
  const int sp = blockIdx.x * 256 + threadIdx.x;
  const int c0 = blockIdx.y * 5, b = blockIdx.z;
  __shared__ float wsh[5][27];
  if (threadIdx.x < 135) wsh[threadIdx.x / 27][threadIdx.x % 27] = w[c0 * 27 + threadIdx.x];
  __syncthreads();
  float acc[5] = {};
  if (sp < 3844) {
    const int oy = sp / 62, ox = sp - oy * 62;
    const float* xb = x + (size_t)b * 3 * 4096 + oy * 64 + ox;
    #pragma unroll
    for (int ic = 0; ic < 3; ic++)
      #pragma unroll
      for (int ky = 0; ky < 3; ky++)
        #pragma unroll
        for (int kx = 0; kx < 3; kx++) {
          const float v = xb[ic * 4096 + ky * 64 + kx];
          const int tap = (ic * 3 + ky) * 3 + kx;
          #pragma unroll
          for (int ol = 0; ol < 5; ol++)
            acc[ol] = fmaf(v, wsh[ol][tap], acc[ol]);
        }
    #pragma unroll
    for (int ol = 0; ol < 5; ol++) {
      acc[ol] += cb[c0 + ol];
      out[(size_t)(b * 20 + c0 + ol) * 3844 + sp] = acc[ol];
    }
  }
  #pragma unroll
  for (int ol = 0; ol < 5; ol++) {
    float v1 = acc[ol], v2 = acc[ol] * acc[ol];
    blockReduce2(v1, v2);
    if (threadIdx.x == 0) {
      ps[(c0 + ol) * 4096 + b * 16 + blockIdx.x] = v1;
      pq[(c0 + ol) * 4096 + b * 16 + blockIdx.x] = v2;
    }
  }
}

// ---------------- conv2: 2x2, ic=20, 40 oc, OCB=8 ----------------
__global__ __launch_bounds__(256) void conv2_kernel(
    const float* __restrict__ in, const float* __restrict__ w, const float* __restrict__ cb,
    float* __restrict__ out, float* __restrict__ ps, float* __restrict__ pq) {
  const int sp = blockIdx.x * 256 + threadIdx.x;
  const int c0 = blockIdx.y * 8, b = blockIdx.z;
  __shared__ float4 wsh4[8][20];   // [ol][ic] = 4 taps
  for (int e = threadIdx.x; e < 160; e += 256)
    wsh4[e / 20][e % 20] = ((const float4*)w)[c0 * 20 + e];
  __syncthreads();
  float acc[8] = {};
  if (sp < 900) {
    const int oy = sp / 30, ox = sp - oy * 30;
    const float* ib = in + (size_t)b * 20 * 961 + oy * 31 + ox;
    #pragma unroll 4
    for (int ic = 0; ic < 20; ic++) {
      const float v0 = ib[ic * 961];
      const float v1 = ib[ic * 961 + 1];
      const float v2 = ib[ic * 961 + 31];
      const float v3 = ib[ic * 961 + 32];
      #pragma unroll
      for (int ol = 0; ol < 8; ol++) {
        const float4 wv = wsh4[ol][ic];
        acc[ol] = fmaf(v0, wv.x, acc[ol]);
        acc[ol] = fmaf(v1, wv.y, acc[ol]);
        acc[ol] = fmaf(v2, wv.z, acc[ol]);
        acc[ol] = fmaf(v3, wv.w, acc[ol]);
      }
    }
    #pragma unroll
    for (int ol = 0; ol < 8; ol++) {
      acc[ol] += cb[c0 + ol];
      out[(size_t)(b * 40 + c0 + ol) * 900 + sp] = acc[ol];
    }
  }
  #pragma unroll
  for (int ol = 0; ol < 8; ol++) {
    float v1 = acc[ol], v2 = acc[ol] * acc[ol];
    blockReduce2(v1, v2);
    if (threadIdx.x == 0) {
      ps[(c0 + ol) * 1024 + b * 4 + blockIdx.x] = v1;
      pq[(c0 + ol) * 1024 + b * 4 + blockIdx.x] = v2;
    }
  }
}

// ---------------- conv3: 2x2, ic=40, 60 oc, OCB=6 ----------------
__global__ __launch_bounds__(256) void conv3_kernel(
    const float* __restrict__ in, const float* __restrict__ w, const float* __restrict__ cb,
    float* __restrict__ out, float* __restrict__ ps, float* __restrict__ pq) {
  const int sp = threadIdx.x;
  const int c0 = blockIdx.y * 6, b = blockIdx.z;
  __shared__ float4 wsh4[6][40];   // [ol][ic]
  if (threadIdx.x < 240)
    wsh4[threadIdx.x / 40][threadIdx.x % 40] = ((const float4*)w)[c0 * 40 + threadIdx.x];
  __syncthreads();
  float acc[6] = {};
  if (sp < 196) {
    const int oy = sp / 14, ox = sp - oy * 14;
    const float* ib = in + (size_t)b * 40 * 225 + oy * 15 + ox;
    #pragma unroll 4
    for (int ic = 0; ic < 40; ic++) {
      const float v0 = ib[ic * 225];
      const float v1 = ib[ic * 225 + 1];
      const float v2 = ib[ic * 225 + 15];
      const float v3 = ib[ic * 225 + 16];
      #pragma unroll
      for (int ol = 0; ol < 6; ol++) {
        const float4 wv = wsh4[ol][ic];
        acc[ol] = fmaf(v0, wv.x, acc[ol]);
        acc[ol] = fmaf(v1, wv.y, acc[ol]);
        acc[ol] = fmaf(v2, wv.z, acc[ol]);
        acc[ol] = fmaf(v3, wv.w, acc[ol]);
      }
    }
    #pragma unroll
    for (int ol = 0; ol < 6; ol++) {
      acc[ol] += cb[c0 + ol];
      out[(size_t)(b * 60 + c0 + ol) * 196 + sp] = acc[ol];
    }
  }
  #pragma unroll
  for (int ol = 0; ol < 6; ol++) {
    float v1 = acc[ol], v2 = acc[ol] * acc[ol];
    blockReduce2(v1, v2);
    if (threadIdx.x == 0) {
      ps[(c0 + ol) * 256 + b] = v1;
      pq[(c0 + ol) * 256 + b] = v2;
    }
  }
}

// ---------------- BN finalize: partials -> scale/shift ----------------
template<int SLOTS>
__global__ __launch_bounds__(256) void bnfin_kernel(
    const float* __restrict__ ps, const float* __restrict__ pq,
    const float* __restrict__ g, const float* __restrict__ bet,
    float* __restrict__ scale, float* __restrict__ shift, float invN) {
  const int c = blockIdx.x;
  float s = 0.f, q = 0.f;
  for (int i = threadIdx.x; i < SLOTS; i += 256) { s += ps[c * SLOTS + i]; q += pq[c * SLOTS + i]; }
  blockReduce2(s, q);
  if (threadIdx.x == 0) {
    const float m = s * invN;
    const float var = q * invN - m * m;
    const float sc = g[c] * rsqrtf(var + EPSF);
    scale[c] = sc;
    shift[c] = bet[c] - m * sc;
  }
}

// ---------------- fused BN + ReLU + 2x2 maxpool (float2 loads) ----------------
template<int C, int Hin, int Win, int Hout, int Wout>
__global__ __launch_bounds__(256) void bnrelupool_kernel(
    const float* __restrict__ in, float* __restrict__ out,
    const float* __restrict__ scale, const float* __restrict__ shift, int total) {
  const int idx = blockIdx.x * 256 + threadIdx.x;
  if (idx >= total) return;
  const int px = idx % Wout;
  int t = idx / Wout;
  const int py = t % Hout; t /= Hout;
  const int c = t % C;
  const int b = t / C;
  const float sc = scale[c], sh = shift[c];
  const float* p = in + ((size_t)(b * C + c) * Hin + 2 * py) * Win + 2 * px;
  const float2 r0 = *(const float2*)p;
  const float2 r1 = *(const float2*)(p + Win);
  float a0 = fmaxf(fmaf(r0.x, sc, sh), 0.f);
  float a1 = fmaxf(fmaf(r0.y, sc, sh), 0.f);
  float a2 = fmaxf(fmaf(r1.x, sc, sh), 0.f);
  float a3 = fmaxf(fmaf(r1.y, sc, sh), 0.f);
  out[idx] = fmaxf(fmaxf(a0, a1), fmaxf(a2, a3));
}

// ---------------- transpose h [256][2940] -> hT [2940][256] ----------------
__global__ __launch_bounds__(256) void transpose_h_kernel(
    const float* __restrict__ in, float* __restrict__ out) {
  __shared__ float tile[64][65];
  const int lx = threadIdx.x & 63, ly = threadIdx.x >> 6;
  const int c0 = blockIdx.x * 64;   // cp dim (2940)
  const int r0 = blockIdx.y * 64;   // b dim (256)
  #pragma unroll
  for (int i = 0; i < 16; i++) {
    const int b = r0 + ly + i * 4;
    const int cp = c0 + lx;
    tile[ly + i * 4][lx] = (cp < 2940) ? in[(size_t)b * 2940 + cp] : 0.f;
  }
  __syncthreads();
  #pragma unroll
  for (int i = 0; i < 16; i++) {
    const int cp = c0 + ly + i * 4;
    if (cp < 2940) out[(size_t)cp * 256 + r0 + lx] = tile[lx][ly + i * 4];
  }
}

// ---------------- LocallyConnected2d (coalesced, o-tiled) ----------------
__global__ __launch_bounds__(256) void lc2_kernel(
    const float* __restrict__ hT, const float* __restrict__ w, const float* __restrict__ lb,
    float* __restrict__ outT, float* __restrict__ ps, float* __restrict__ pq) {
  const int sp = blockIdx.x;
  const int o0 = blockIdx.y * 8;
  const int b = threadIdx.x;
  __shared__ float wsh[8 * 240];
  for (int e = threadIdx.x; e < 1920; e += 256) {
    const int ol = e / 240, ck = e - ol * 240;
    const int c = ck >> 2, k = ck & 3;
    wsh[e] = w[((size_t)((o0 + ol) * 60 + c) * 36 + sp) * 4 + k];
  }
  __syncthreads();
  const int i = sp / 6, j = sp - i * 6;
  const int pos0 = i * 7 + j;
  float acc[8] = {};
  #pragma unroll 4
  for (int c = 0; c < 60; c++) {
    const float h0 = hT[(size_t)(c * 49 + pos0) * 256 + b];
    const float h1 = hT[(size_t)(c * 49 + pos0 + 1) * 256 + b];
    const float h2 = hT[(size_t)(c * 49 + pos0 + 7) * 256 + b];
    const float h3 = hT[(size_t)(c * 49 + pos0 + 8) * 256 + b];
    #pragma unroll
    for (int ol = 0; ol < 8; ol++) {
      const float* wp = &wsh[ol * 240 + c * 4];
      acc[ol] = fmaf(h0, wp[0], acc[ol]);
      acc[ol] = fmaf(h1, wp[1], acc[ol]);
      acc[ol] = fmaf(h2, wp[2], acc[ol]);
      acc[ol] = fmaf(h3, wp[3], acc[ol]);
    }
  }
  #pragma unroll
  for (int ol = 0; ol < 8; ol++) {
    const int o = o0 + ol;
    const float val = acc[ol] + lb[o * 36 + sp];
    outT[(size_t)(o * 36 + sp) * 256 + b] = val;
    float v1 = val, v2 = val * val;
    blockReduce2(v1, v2);
    if (threadIdx.x == 0) { ps[o * 36 + sp] = v1; pq[o * 36 + sp] = v2; }
  }
}

// ---------------- lcpost: BN+ReLU + transpose lcT [2880][256] -> x2 [256][2880] ----
__global__ __launch_bounds__(256) void lcpost2_kernel(
    const float* __restrict__ inT, float* __restrict__ out,
    const float* __restrict__ scale, const float* __restrict__ shift) {
  __shared__ float tile[64][65];
  const int lx = threadIdx.x & 63, ly = threadIdx.x >> 6;
  const int k0 = blockIdx.x * 64;   // k dim (2880)
  const int b0 = blockIdx.y * 64;   // b dim (256)
  #pragma unroll
  for (int i = 0; i < 16; i++) {
    const int k = k0 + ly + i * 4;
    const int o = k / 36;
    const float v = inT[(size_t)k * 256 + b0 + lx];
    tile[ly + i * 4][lx] = fmaxf(fmaf(v, scale[o], shift[o]), 0.f);
  }
  __syncthreads();
  #pragma unroll
  for (int i = 0; i < 16; i++) {
    const int b = b0 + ly + i * 4;
    out[(size_t)b * 2880 + k0 + lx] = tile[lx][ly + i * 4];
  }
}

// ---------------- FC GEMM: [256,5820] x [768,5820]^T, split-K atomics ----------------
__global__ __launch_bounds__(256) void fc_gemm_kernel(
    const float* __restrict__ h, const float* __restrict__ x2,
    const float* __restrict__ W, float* __restrict__ Y) {
  const int m0 = blockIdx.x * 64;
  const int n0 = blockIdx.y * 64;
  const int tid = threadIdx.x;
  const int tx = tid & 15, ty = tid >> 4;
  __shared__ float As[16][68];
  __shared__ float Ws[16][68];
  float acc[4][4] = {};
  const int kbeg = blockIdx.z * 736;
  const int kend = (kbeg + 736 < 5820) ? (kbeg + 736) : 5820;
  for (int k0 = kbeg; k0 < kend; k0 += 16) {
    #pragma unroll
    for (int l = 0; l < 4; l++) {
      const int e = tid + l * 256;
      const int r = e >> 4, kk = e & 15;
      const int k = k0 + kk;
      float av = 0.f, wv = 0.f;
      if (k < 5820) {
        const int mb = m0 + r;
        av = (k < 2940) ? h[mb * 2940 + k] : x2[mb * 2880 + (k - 2940)];
        wv = W[(size_t)(n0 + r) * 5820 + k];
      }
      As[kk][r] = av;
      Ws[kk][r] = wv;
    }
    __syncthreads();
    #pragma unroll
    for (int kk = 0; kk < 16; kk++) {
      const float4 a4 = *(const float4*)&As[kk][ty * 4];
      const float4 b4 = *(const float4*)&Ws[kk][tx * 4];
      const float a[4] = {a4.x, a4.y, a4.z, a4.w};
      const float bb[4] = {b4.x, b4.y, b4.z, b4.w};
      #pragma unroll
      for (int ii = 0; ii < 4; ii++)
        #pragma unroll
        for (int jj = 0; jj < 4; jj++)
          acc[ii][jj] = fmaf(a[ii], bb[jj], acc[ii][jj]);
    }
    __syncthreads();
  }
  #pragma unroll
  for (int ii = 0; ii < 4; ii++)
    #pragma unroll
    for (int jj = 0; jj < 4; jj++)
      atomicAdd(&Y[(size_t)(m0 + ty * 4 + ii) * 768 + (n0 + tx * 4 + jj)], acc[ii][jj]);
}

// ---------------- BN5 stats (per-feature over batch), coalesced ----------------
__global__ __launch_bounds__(256) void bn5_stats_kernel(
    const float* __restrict__ Y, const float* __restrict__ g, const float* __restrict__ bet,
    float* __restrict__ scale, float* __restrict__ shift) {
  const int tx = threadIdx.x & 63, ty = threadIdx.x >> 6;
  const int n = blockIdx.x * 64 + tx;
  float s = 0.f, q = 0.f;
  for (int bi = 0; bi < 64; bi++) {
    const float v = Y[(size_t)(bi * 4 + ty) * 768 + n];
    s += v; q += v * v;
  }
  __shared__ float rs[4][64], rq[4][64];
  rs[ty][tx] = s; rq[ty][tx] = q;
  __syncthreads();
  if (ty == 0) {
    s = rs[0][tx] + rs[1][tx] + rs[2][tx] + rs[3][tx];
    q = rq[0][tx] + rq[1][tx] + rq[2][tx] + rq[3][tx];
    const float m = s * (1.f / 256.f);
    const float var = q * (1.f / 256.f) - m * m;
    const float sc = g[n] * rsqrtf(var + EPSF);
    scale[n] = sc;
    shift[n] = bet[n] - m * sc;
  }
}

// ---------------- final fuse ----------------
__global__ __launch_bounds__(256) void final_kernel(
    const float* __restrict__ Y, const float* __restrict__ scale, const float* __restrict__ shift,
    const float* __restrict__ fw, const float* __restrict__ fb, float* __restrict__ out) {
  const int idx = blockIdx.x * 256 + threadIdx.x;  // 12288 exact
  const int b = idx / 48, hh = idx - b * 48;
  const float* yb = Y + (size_t)b * 768 + hh * 16;
  const float* sc = scale + hh * 16;
  const float* sh = shift + hh * 16;
  const float* w = fw + hh * 16;
  float acc = fb[hh];
  #pragma unroll
  for (int s = 0; s < 16; s++)
    acc += fmaxf(fmaf(yb[s], sc[s], sh[s]), 0.f) * w[s];
  out[idx] = acc;
}

// ---------------- launch ----------------
extern "C" void kernel_launch(void* const* d_in, const int* in_sizes, int n_in,
                              void* d_out, int out_size, void* d_ws, size_t ws_size,
                              hipStream_t stream) {
  const float* x   = (const float*)d_in[0];
  const float* c1w = (const float*)d_in[1];
  const float* c1b = (const float*)d_in[2];
  const float* g1  = (const float*)d_in[3];
  const float* b1  = (const float*)d_in[4];
  const float* c2w = (const float*)d_in[5];
  const float* c2b = (const float*)d_in[6];
  const float* g2  = (const float*)d_in[7];
  const float* b2  = (const float*)d_in[8];
  const float* c3w = (const float*)d_in[9];
  const float* c3b = (const float*)d_in[10];
  const float* g3  = (const float*)d_in[11];
  const float* b3  = (const float*)d_in[12];
  const float* lcw = (const float*)d_in[13];
  const float* lcb = (const float*)d_in[14];
  const float* g4  = (const float*)d_in[15];
  const float* b4  = (const float*)d_in[16];
  const float* fcw = (const float*)d_in[17];
  const float* g5  = (const float*)d_in[19];
  const float* b5  = (const float*)d_in[20];
  const float* fw  = (const float*)d_in[21];
  const float* fb  = (const float*)d_in[22];

  float* ws = (float*)d_ws;
  float* A  = ws + OFF_A;   // conv raw / lcT
  float* B_ = ws + OFF_B;   // pool1/pool2 / hT
  float* C_ = ws + OFF_C;   // h (x1)
  float* D_ = ws + OFF_D;   // x2
  float* Y  = ws + OFF_Y;

  hipMemsetAsync(Y, 0, 196608 * sizeof(float), stream);

  // stage 1
  conv1_kernel<<<dim3(16, 4, 256), 256, 0, stream>>>(x, c1w, c1b, A, ws + P1S, ws + P1Q);
  bnfin_kernel<4096><<<20, 256, 0, stream>>>(ws + P1S, ws + P1Q, g1, b1, ws + SC1, ws + SH1, 1.f / 984064.f);
  bnrelupool_kernel<20, 62, 62, 31, 31><<<19220, 256, 0, stream>>>(A, B_, ws + SC1, ws + SH1, 4920320);
  // stage 2
  conv2_kernel<<<dim3(4, 5, 256), 256, 0, stream>>>(B_, c2w, c2b, A, ws + P2S, ws + P2Q);
  bnfin_kernel<1024><<<40, 256, 0, stream>>>(ws + P2S, ws + P2Q, g2, b2, ws + SC2, ws + SH2, 1.f / 230400.f);
  bnrelupool_kernel<40, 30, 30, 15, 15><<<9000, 256, 0, stream>>>(A, B_, ws + SC2, ws + SH2, 2304000);
  // stage 3
  conv3_kernel<<<dim3(1, 10, 256), 256, 0, stream>>>(B_, c3w, c3b, A, ws + P3S, ws + P3Q);
  bnfin_kernel<256><<<60, 256, 0, stream>>>(ws + P3S, ws + P3Q, g3, b3, ws + SC3, ws + SH3, 1.f / 50176.f);
  bnrelupool_kernel<60, 14, 14, 7, 7><<<2940, 256, 0, stream>>>(A, C_, ws + SC3, ws + SH3, 752640);
  // h -> hT
  transpose_h_kernel<<<dim3(46, 4), 256, 0, stream>>>(C_, B_);
  // locally connected (coalesced): lcT into A
  lc2_kernel<<<dim3(36, 10), 256, 0, stream>>>(B_, lcw, lcb, A, ws + P4S, ws + P4Q);
  bnfin_kernel<36><<<80, 256, 0, stream>>>(ws + P4S, ws + P4Q, g4, b4, ws + SC4, ws + SH4, 1.f / 9216.f);
  lcpost2_kernel<<<dim3(45, 4), 256, 0, stream>>>(A, D_, ws + SC4, ws + SH4);
  // fc (fc_b cancels under BN1d)
  fc_gemm_kernel<<<dim3(4, 12, 8), 256, 0, stream>>>(C_, D_, fcw, Y);
  bn5_stats_kernel<<<12, 256, 0, stream>>>(Y, g5, b5, ws + SC5, ws + SH5);
  final_kernel<<<48, 256, 0, stream>>>(Y, ws + SC5, ws + SH5, fw, fb, (float*)d_out);
}

// Round 7
// 412.481 us; speedup vs baseline: 2.1661x; 1.1333x over previous
//
#include <hip/hip_runtime.h>

#define EPSF 1e-5f

// ---------------- workspace layout (float offsets) ----------------
#define P1S 0          // [20][4096]
#define P1Q 81920
#define P2S 163840     // [40][1024]
#define P2Q 204800
#define P3S 245760     // [60][256]
#define P3Q 261120
#define P4S 276480     // [80][36]
#define P4Q 279360
#define SC1 282240
#define SH1 282260
#define SC2 282280
#define SH2 282320
#define SC3 282360
#define SH3 282420
#define SC4 282480
#define SH4 282560
#define SC5 282640     // [768]
#define SH5 283408

#define OFF_A 524288            // conv2raw/conv3raw/lcT, then featB/WB (19.6M cap)
#define OFF_B 20205568          // pool1/pool2/hT (4.9M cap)
#define OFF_C 25125888          // h (x1): 752,640
#define OFF_D 25878528          // x2: 737,280
#define OFF_Y 26615808          // y: 196,608

#define KP 6144                 // padded K for bf16 GEMM (5820 -> 6144 = 4*1536)

// ---------------- helpers ----------------
__device__ __forceinline__ void blockReduce2(float& v1, float& v2) {
  __syncthreads();  // protects shared buffer across repeated calls
  #pragma unroll
  for (int off = 32; off > 0; off >>= 1) {
    v1 += __shfl_down(v1, off);
    v2 += __shfl_down(v2, off);
  }
  __shared__ float s1[4], s2[4];
  const int wid = threadIdx.x >> 6, lane = threadIdx.x & 63;
  if (lane == 0) { s1[wid] = v1; s2[wid] = v2; }
  __syncthreads();
  if (threadIdx.x == 0) { v1 = s1[0]+s1[1]+s1[2]+s1[3]; v2 = s2[0]+s2[1]+s2[2]+s2[3]; }
}

__device__ __forceinline__ unsigned short f2bf(float f) {
  unsigned int u = __float_as_uint(f);
  return (unsigned short)((u + 0x7FFFu + ((u >> 16) & 1u)) >> 16);
}

// ---------------- conv1 stats: 3x3, ic=3, OCB=5, NO raw store ----------------
__global__ __launch_bounds__(256) void conv1_stats_kernel(
    const float* __restrict__ x, const float* __restrict__ w, const float* __restrict__ cb,
    float* __restrict__ ps, float* __restrict__ pq) {
  const int sp = blockIdx.x * 256 + threadIdx.x;
  const int c0 = blockIdx.y * 5, b = blockIdx.z;
  __shared__ float wsh[5][27];
  if (threadIdx.x < 135) wsh[threadIdx.x / 27][threadIdx.x % 27] = w[c0 * 27 + threadIdx.x];
  __syncthreads();
  float acc[5] = {};
  if (sp < 3844) {
    const int oy = sp / 62, ox = sp - oy * 62;
    const float* xb = x + (size_t)b * 3 * 4096 + oy * 64 + ox;
    #pragma unroll
    for (int ic = 0; ic < 3; ic++)
      #pragma unroll
      for (int ky = 0; ky < 3; ky++)
        #pragma unroll
        for (int kx = 0; kx < 3; kx++) {
          const float v = xb[ic * 4096 + ky * 64 + kx];
          const int tap = (ic * 3 + ky) * 3 + kx;
          #pragma unroll
          for (int ol = 0; ol < 5; ol++)
            acc[ol] = fmaf(v, wsh[ol][tap], acc[ol]);
        }
    #pragma unroll
    for (int ol = 0; ol < 5; ol++) acc[ol] += cb[c0 + ol];
  }
  #pragma unroll
  for (int ol = 0; ol < 5; ol++) {
    float v1 = acc[ol], v2 = acc[ol] * acc[ol];
    blockReduce2(v1, v2);
    if (threadIdx.x == 0) {
      ps[(c0 + ol) * 4096 + b * 16 + blockIdx.x] = v1;
      pq[(c0 + ol) * 4096 + b * 16 + blockIdx.x] = v2;
    }
  }
}

// ---------------- fused conv1 + BN + ReLU + pool: recompute, write pooled only ----
__global__ __launch_bounds__(256) void convpool1_kernel(
    const float* __restrict__ x, const float* __restrict__ w, const float* __restrict__ cb,
    const float* __restrict__ scale, const float* __restrict__ shift,
    float* __restrict__ out) {
  const int sp = blockIdx.x * 256 + threadIdx.x;  // pooled pixel, 961
  const int c0 = blockIdx.y * 5, b = blockIdx.z;
  __shared__ float wsh[5][27];
  if (threadIdx.x < 135) wsh[threadIdx.x / 27][threadIdx.x % 27] = w[c0 * 27 + threadIdx.x];
  __syncthreads();
  if (sp >= 961) return;
  const int py = sp / 31, px = sp - py * 31;
  const float* xb = x + (size_t)b * 3 * 4096 + (2 * py) * 64 + 2 * px;
  float acc[5][4] = {};
  #pragma unroll
  for (int ic = 0; ic < 3; ic++) {
    float v[4][4];
    #pragma unroll
    for (int r = 0; r < 4; r++)
      #pragma unroll
      for (int cc = 0; cc < 4; cc++)
        v[r][cc] = xb[ic * 4096 + r * 64 + cc];
    #pragma unroll
    for (int ol = 0; ol < 5; ol++)
      #pragma unroll
      for (int dy = 0; dy < 2; dy++)
        #pragma unroll
        for (int dx = 0; dx < 2; dx++) {
          float a = acc[ol][dy * 2 + dx];
          #pragma unroll
          for (int ky = 0; ky < 3; ky++)
            #pragma unroll
            for (int kx = 0; kx < 3; kx++)
              a = fmaf(v[dy + ky][dx + kx], wsh[ol][(ic * 3 + ky) * 3 + kx], a);
          acc[ol][dy * 2 + dx] = a;
        }
  }
  #pragma unroll
  for (int ol = 0; ol < 5; ol++) {
    const float sc = scale[c0 + ol];
    const float sh = fmaf(cb[c0 + ol], sc, shift[c0 + ol]);  // fold conv bias
    float m = -1e30f;
    #pragma unroll
    for (int q = 0; q < 4; q++)
      m = fmaxf(m, fmaxf(fmaf(acc[ol][q], sc, sh), 0.f));
    out[(size_t)(b * 20 + c0 + ol) * 961 + sp] = m;
  }
}

// ---------------- conv2: 2x2, ic=20, 40 oc, OCB=8 ----------------
__global__ __launch_bounds__(256) void conv2_kernel(
    const float* __restrict__ in, const float* __restrict__ w, const float* __restrict__ cb,
    float* __restrict__ out, float* __restrict__ ps, float* __restrict__ pq) {
  const int sp = blockIdx.x * 256 + threadIdx.x;
  const int c0 = blockIdx.y * 8, b = blockIdx.z;
  __shared__ float4 wsh4[8][20];   // [ol][ic] = 4 taps
  for (int e = threadIdx.x; e < 160; e += 256)
    wsh4[e / 20][e % 20] = ((const float4*)w)[c0 * 20 + e];
  __syncthreads();
  float acc[8] = {};
  if (sp < 900) {
    const int oy = sp / 30, ox = sp - oy * 30;
    const float* ib = in + (size_t)b * 20 * 961 + oy * 31 + ox;
    #pragma unroll 4
    for (int ic = 0; ic < 20; ic++) {
      const float v0 = ib[ic * 961];
      const float v1 = ib[ic * 961 + 1];
      const float v2 = ib[ic * 961 + 31];
      const float v3 = ib[ic * 961 + 32];
      #pragma unroll
      for (int ol = 0; ol < 8; ol++) {
        const float4 wv = wsh4[ol][ic];
        acc[ol] = fmaf(v0, wv.x, acc[ol]);
        acc[ol] = fmaf(v1, wv.y, acc[ol]);
        acc[ol] = fmaf(v2, wv.z, acc[ol]);
        acc[ol] = fmaf(v3, wv.w, acc[ol]);
      }
    }
    #pragma unroll
    for (int ol = 0; ol < 8; ol++) {
      acc[ol] += cb[c0 + ol];
      out[(size_t)(b * 40 + c0 + ol) * 900 + sp] = acc[ol];
    }
  }
  #pragma unroll
  for (int ol = 0; ol < 8; ol++) {
    float v1 = acc[ol], v2 = acc[ol] * acc[ol];
    blockReduce2(v1, v2);
    if (threadIdx.x == 0) {
      ps[(c0 + ol) * 1024 + b * 4 + blockIdx.x] = v1;
      pq[(c0 + ol) * 1024 + b * 4 + blockIdx.x] = v2;
    }
  }
}

// ---------------- conv3: 2x2, ic=40, 60 oc, OCB=6 ----------------
__global__ __launch_bounds__(256) void conv3_kernel(
    const float* __restrict__ in, const float* __restrict__ w, const float* __restrict__ cb,
    float* __restrict__ out, float* __restrict__ ps, float* __restrict__ pq) {
  const int sp = threadIdx.x;
  const int c0 = blockIdx.y * 6, b = blockIdx.z;
  __shared__ float4 wsh4[6][40];   // [ol][ic]
  if (threadIdx.x < 240)
    wsh4[threadIdx.x / 40][threadIdx.x % 40] = ((const float4*)w)[c0 * 40 + threadIdx.x];
  __syncthreads();
  float acc[6] = {};
  if (sp < 196) {
    const int oy = sp / 14, ox = sp - oy * 14;
    const float* ib = in + (size_t)b * 40 * 225 + oy * 15 + ox;
    #pragma unroll 4
    for (int ic = 0; ic < 40; ic++) {
      const float v0 = ib[ic * 225];
      const float v1 = ib[ic * 225 + 1];
      const float v2 = ib[ic * 225 + 15];
      const float v3 = ib[ic * 225 + 16];
      #pragma unroll
      for (int ol = 0; ol < 6; ol++) {
        const float4 wv = wsh4[ol][ic];
        acc[ol] = fmaf(v0, wv.x, acc[ol]);
        acc[ol] = fmaf(v1, wv.y, acc[ol]);
        acc[ol] = fmaf(v2, wv.z, acc[ol]);
        acc[ol] = fmaf(v3, wv.w, acc[ol]);
      }
    }
    #pragma unroll
    for (int ol = 0; ol < 6; ol++) {
      acc[ol] += cb[c0 + ol];
      out[(size_t)(b * 60 + c0 + ol) * 196 + sp] = acc[ol];
    }
  }
  #pragma unroll
  for (int ol = 0; ol < 6; ol++) {
    float v1 = acc[ol], v2 = acc[ol] * acc[ol];
    blockReduce2(v1, v2);
    if (threadIdx.x == 0) {
      ps[(c0 + ol) * 256 + b] = v1;
      pq[(c0 + ol) * 256 + b] = v2;
    }
  }
}

// ---------------- BN finalize: partials -> scale/shift ----------------
template<int SLOTS>
__global__ __launch_bounds__(256) void bnfin_kernel(
    const float* __restrict__ ps, const float* __restrict__ pq,
    const float* __restrict__ g, const float* __restrict__ bet,
    float* __restrict__ scale, float* __restrict__ shift, float invN) {
  const int c = blockIdx.x;
  float s = 0.f, q = 0.f;
  for (int i = threadIdx.x; i < SLOTS; i += 256) { s += ps[c * SLOTS + i]; q += pq[c * SLOTS + i]; }
  blockReduce2(s, q);
  if (threadIdx.x == 0) {
    const float m = s * invN;
    const float var = q * invN - m * m;
    const float sc = g[c] * rsqrtf(var + EPSF);
    scale[c] = sc;
    shift[c] = bet[c] - m * sc;
  }
}

// ---------------- fused BN + ReLU + 2x2 maxpool (float2 loads) ----------------
template<int C, int Hin, int Win, int Hout, int Wout>
__global__ __launch_bounds__(256) void bnrelupool_kernel(
    const float* __restrict__ in, float* __restrict__ out,
    const float* __restrict__ scale, const float* __restrict__ shift, int total) {
  const int idx = blockIdx.x * 256 + threadIdx.x;
  if (idx >= total) return;
  const int px = idx % Wout;
  int t = idx / Wout;
  const int py = t % Hout; t /= Hout;
  const int c = t % C;
  const int b = t / C;
  const float sc = scale[c], sh = shift[c];
  const float* p = in + ((size_t)(b * C + c) * Hin + 2 * py) * Win + 2 * px;
  const float2 r0 = *(const float2*)p;
  const float2 r1 = *(const float2*)(p + Win);
  float a0 = fmaxf(fmaf(r0.x, sc, sh), 0.f);
  float a1 = fmaxf(fmaf(r0.y, sc, sh), 0.f);
  float a2 = fmaxf(fmaf(r1.x, sc, sh), 0.f);
  float a3 = fmaxf(fmaf(r1.y, sc, sh), 0.f);
  out[idx] = fmaxf(fmaxf(a0, a1), fmaxf(a2, a3));
}

// ---------------- transpose h [256][2940] -> hT [2940][256] ----------------
__global__ __launch_bounds__(256) void transpose_h_kernel(
    const float* __restrict__ in, float* __restrict__ out) {
  __shared__ float tile[64][65];
  const int lx = threadIdx.x & 63, ly = threadIdx.x >> 6;
  const int c0 = blockIdx.x * 64;   // cp dim (2940)
  const int r0 = blockIdx.y * 64;   // b dim (256)
  #pragma unroll
  for (int i = 0; i < 16; i++) {
    const int b = r0 + ly + i * 4;
    const int cp = c0 + lx;
    tile[ly + i * 4][lx] = (cp < 2940) ? in[(size_t)b * 2940 + cp] : 0.f;
  }
  __syncthreads();
  #pragma unroll
  for (int i = 0; i < 16; i++) {
    const int cp = c0 + ly + i * 4;
    if (cp < 2940) out[(size_t)cp * 256 + r0 + lx] = tile[lx][ly + i * 4];
  }
}

// ---------------- LocallyConnected2d (coalesced, o-tiled) ----------------
__global__ __launch_bounds__(256) void lc2_kernel(
    const float* __restrict__ hT, const float* __restrict__ w, const float* __restrict__ lb,
    float* __restrict__ outT, float* __restrict__ ps, float* __restrict__ pq) {
  const int sp = blockIdx.x;
  const int o0 = blockIdx.y * 8;
  const int b = threadIdx.x;
  __shared__ float wsh[8 * 240];
  for (int e = threadIdx.x; e < 1920; e += 256) {
    const int ol = e / 240, ck = e - ol * 240;
    const int c = ck >> 2, k = ck & 3;
    wsh[e] = w[((size_t)((o0 + ol) * 60 + c) * 36 + sp) * 4 + k];
  }
  __syncthreads();
  const int i = sp / 6, j = sp - i * 6;
  const int pos0 = i * 7 + j;
  float acc[8] = {};
  #pragma unroll 4
  for (int c = 0; c < 60; c++) {
    const float h0 = hT[(size_t)(c * 49 + pos0) * 256 + b];
    const float h1 = hT[(size_t)(c * 49 + pos0 + 1) * 256 + b];
    const float h2 = hT[(size_t)(c * 49 + pos0 + 7) * 256 + b];
    const float h3 = hT[(size_t)(c * 49 + pos0 + 8) * 256 + b];
    #pragma unroll
    for (int ol = 0; ol < 8; ol++) {
      const float* wp = &wsh[ol * 240 + c * 4];
      acc[ol] = fmaf(h0, wp[0], acc[ol]);
      acc[ol] = fmaf(h1, wp[1], acc[ol]);
      acc[ol] = fmaf(h2, wp[2], acc[ol]);
      acc[ol] = fmaf(h3, wp[3], acc[ol]);
    }
  }
  #pragma unroll
  for (int ol = 0; ol < 8; ol++) {
    const int o = o0 + ol;
    const float val = acc[ol] + lb[o * 36 + sp];
    outT[(size_t)(o * 36 + sp) * 256 + b] = val;
    float v1 = val, v2 = val * val;
    blockReduce2(v1, v2);
    if (threadIdx.x == 0) { ps[o * 36 + sp] = v1; pq[o * 36 + sp] = v2; }
  }
}

// ---------------- lcpost: BN+ReLU + transpose lcT [2880][256] -> x2 [256][2880] ----
__global__ __launch_bounds__(256) void lcpost2_kernel(
    const float* __restrict__ inT, float* __restrict__ out,
    const float* __restrict__ scale, const float* __restrict__ shift) {
  __shared__ float tile[64][65];
  const int lx = threadIdx.x & 63, ly = threadIdx.x >> 6;
  const int k0 = blockIdx.x * 64;   // k dim (2880)
  const int b0 = blockIdx.y * 64;   // b dim (256)
  #pragma unroll
  for (int i = 0; i < 16; i++) {
    const int k = k0 + ly + i * 4;
    const int o = k / 36;
    const float v = inT[(size_t)k * 256 + b0 + lx];
    tile[ly + i * 4][lx] = fmaxf(fmaf(v, scale[o], shift[o]), 0.f);
  }
  __syncthreads();
  #pragma unroll
  for (int i = 0; i < 16; i++) {
    const int b = b0 + ly + i * 4;
    out[(size_t)b * 2880 + k0 + lx] = tile[lx][ly + i * 4];
  }
}

// ---------------- pack feat [256][KP] bf16 from h(2940) + x2(2880), zero tail ----
__global__ __launch_bounds__(256) void pack_feat_kernel(
    const float* __restrict__ h, const float* __restrict__ x2, unsigned short* __restrict__ fB) {
  const int idx = blockIdx.x * 256 + threadIdx.x;  // 256*1536 exact
  const int b = idx / 1536, kq = idx - b * 1536;
  const int k0 = kq * 4;
  ushort4 o;
  float v[4];
  #pragma unroll
  for (int q = 0; q < 4; q++) {
    const int k = k0 + q;
    v[q] = (k < 2940) ? h[(size_t)b * 2940 + k]
         : (k < 5820) ? x2[(size_t)b * 2880 + (k - 2940)] : 0.f;
  }
  o.x = f2bf(v[0]); o.y = f2bf(v[1]); o.z = f2bf(v[2]); o.w = f2bf(v[3]);
  *(ushort4*)&fB[(size_t)b * KP + k0] = o;
}

// ---------------- pack W [768][KP] bf16 from fcw [768][5820], zero tail --------
__global__ __launch_bounds__(256) void pack_w_kernel(
    const float* __restrict__ W, unsigned short* __restrict__ WBp) {
  const int idx = blockIdx.x * 256 + threadIdx.x;  // 768*1536 exact
  const int n = idx / 1536, kq = idx - n * 1536;
  const int k0 = kq * 4;
  ushort4 o;
  float v[4];
  #pragma unroll
  for (int q = 0; q < 4; q++) {
    const int k = k0 + q;
    v[q] = (k < 5820) ? W[(size_t)n * 5820 + k] : 0.f;
  }
  o.x = f2bf(v[0]); o.y = f2bf(v[1]); o.z = f2bf(v[2]); o.w = f2bf(v[3]);
  *(ushort4*)&WBp[(size_t)n * KP + k0] = o;
}

// ---------------- FC GEMM via bf16 MFMA: 64x64 tiles, split-K=4, atomics -------
typedef __attribute__((ext_vector_type(4))) float f32x4;
typedef __attribute__((ext_vector_type(8))) short bf16x8;

__global__ __launch_bounds__(256) void fc_mfma_kernel(
    const unsigned short* __restrict__ fB, const unsigned short* __restrict__ WBp,
    float* __restrict__ Y) {
  const int wid = threadIdx.x >> 6, l = threadIdx.x & 63;
  const int wy = wid >> 1, wx = wid & 1;
  const int m0 = blockIdx.x * 64 + wy * 32;
  const int n0 = blockIdx.y * 64 + wx * 32;
  const int lrow = l & 15, lk = (l >> 4) * 8;
  const unsigned short* ap = fB + (size_t)(m0 + lrow) * KP + lk;
  const unsigned short* bp = WBp + (size_t)(n0 + lrow) * KP + lk;
  f32x4 acc[2][2] = {};
  const int kbase = blockIdx.z * 1536;
  #pragma unroll 4
  for (int s = 0; s < 48; s++) {
    const int k = kbase + s * 32;
    const bf16x8 a0 = *(const bf16x8*)(ap + k);
    const bf16x8 a1 = *(const bf16x8*)(ap + 16 * KP + k);
    const bf16x8 b0 = *(const bf16x8*)(bp + k);
    const bf16x8 b1 = *(const bf16x8*)(bp + 16 * KP + k);
    acc[0][0] = __builtin_amdgcn_mfma_f32_16x16x32_bf16(a0, b0, acc[0][0], 0, 0, 0);
    acc[0][1] = __builtin_amdgcn_mfma_f32_16x16x32_bf16(a0, b1, acc[0][1], 0, 0, 0);
    acc[1][0] = __builtin_amdgcn_mfma_f32_16x16x32_bf16(a1, b0, acc[1][0], 0, 0, 0);
    acc[1][1] = __builtin_amdgcn_mfma_f32_16x16x32_bf16(a1, b1, acc[1][1], 0, 0, 0);
  }
  const int orow = (l >> 4) * 4, ocol = l & 15;
  #pragma unroll
  for (int fi = 0; fi < 2; fi++)
    #pragma unroll
    for (int fj = 0; fj < 2; fj++)
      #pragma unroll
      for (int r = 0; r < 4; r++)
        atomicAdd(&Y[(size_t)(m0 + fi * 16 + orow + r) * 768 + n0 + fj * 16 + ocol],
                  acc[fi][fj][r]);
}

// ---------------- BN5 stats (per-feature over batch), coalesced ----------------
__global__ __launch_bounds__(256) void bn5_stats_kernel(
    const float* __restrict__ Y, const float* __restrict__ g, const float* __restrict__ bet,
    float* __restrict__ scale, float* __restrict__ shift) {
  const int tx = threadIdx.x & 63, ty = threadIdx.x >> 6;
  const int n = blockIdx.x * 64 + tx;
  float s = 0.f, q = 0.f;
  for (int bi = 0; bi < 64; bi++) {
    const float v = Y[(size_t)(bi * 4 + ty) * 768 + n];
    s += v; q += v * v;
  }
  __shared__ float rs[4][64], rq[4][64];
  rs[ty][tx] = s; rq[ty][tx] = q;
  __syncthreads();
  if (ty == 0) {
    s = rs[0][tx] + rs[1][tx] + rs[2][tx] + rs[3][tx];
    q = rq[0][tx] + rq[1][tx] + rq[2][tx] + rq[3][tx];
    const float m = s * (1.f / 256.f);
    const float var = q * (1.f / 256.f) - m * m;
    const float sc = g[n] * rsqrtf(var + EPSF);
    scale[n] = sc;
    shift[n] = bet[n] - m * sc;
  }
}

// ---------------- final fuse ----------------
__global__ __launch_bounds__(256) void final_kernel(
    const float* __restrict__ Y, const float* __restrict__ scale, const float* __restrict__ shift,
    const float* __restrict__ fw, const float* __restrict__ fb, float* __restrict__ out) {
  const int idx = blockIdx.x * 256 + threadIdx.x;  // 12288 exact
  const int b = idx / 48, hh = idx - b * 48;
  const float* yb = Y + (size_t)b * 768 + hh * 16;
  const float* sc = scale + hh * 16;
  const float* sh = shift + hh * 16;
  const float* w = fw + hh * 16;
  float acc = fb[hh];
  #pragma unroll
  for (int s = 0; s < 16; s++)
    acc += fmaxf(fmaf(yb[s], sc[s], sh[s]), 0.f) * w[s];
  out[idx] = acc;
}

// ---------------- launch ----------------
extern "C" void kernel_launch(void* const* d_in, const int* in_sizes, int n_in,
                              void* d_out, int out_size, void* d_ws, size_t ws_size,
                              hipStream_t stream) {
  const float* x   = (const float*)d_in[0];
  const float* c1w = (const float*)d_in[1];
  const float* c1b = (const float*)d_in[2];
  const float* g1  = (const float*)d_in[3];
  const float* b1  = (const float*)d_in[4];
  const float* c2w = (const float*)d_in[5];
  const float* c2b = (const float*)d_in[6];
  const float* g2  = (const float*)d_in[7];
  const float* b2  = (const float*)d_in[8];
  const float* c3w = (const float*)d_in[9];
  const float* c3b = (const float*)d_in[10];
  const float* g3  = (const float*)d_in[11];
  const float* b3  = (const float*)d_in[12];
  const float* lcw = (const float*)d_in[13];
  const float* lcb = (const float*)d_in[14];
  const float* g4  = (const float*)d_in[15];
  const float* b4  = (const float*)d_in[16];
  const float* fcw = (const float*)d_in[17];
  const float* g5  = (const float*)d_in[19];
  const float* b5  = (const float*)d_in[20];
  const float* fw  = (const float*)d_in[21];
  const float* fb  = (const float*)d_in[22];

  float* ws = (float*)d_ws;
  float* A  = ws + OFF_A;   // conv2/3 raw, lcT; later featB/WB
  float* B_ = ws + OFF_B;   // pool1/pool2/hT
  float* C_ = ws + OFF_C;   // h (x1)
  float* D_ = ws + OFF_D;   // x2
  float* Y  = ws + OFF_Y;
  unsigned short* featB = (unsigned short*)A;                 // 256*KP bf16 = 786432 floats
  unsigned short* WB    = (unsigned short*)(A + 786432);      // FIX: was A+524288 (overlapped featB)

  hipMemsetAsync(Y, 0, 196608 * sizeof(float), stream);

  // stage 1: stats (no store) -> finalize -> fused conv+BN+ReLU+pool
  conv1_stats_kernel<<<dim3(16, 4, 256), 256, 0, stream>>>(x, c1w, c1b, ws + P1S, ws + P1Q);
  bnfin_kernel<4096><<<20, 256, 0, stream>>>(ws + P1S, ws + P1Q, g1, b1, ws + SC1, ws + SH1, 1.f / 984064.f);
  convpool1_kernel<<<dim3(4, 4, 256), 256, 0, stream>>>(x, c1w, c1b, ws + SC1, ws + SH1, B_);
  // stage 2
  conv2_kernel<<<dim3(4, 5, 256), 256, 0, stream>>>(B_, c2w, c2b, A, ws + P2S, ws + P2Q);
  bnfin_kernel<1024><<<40, 256, 0, stream>>>(ws + P2S, ws + P2Q, g2, b2, ws + SC2, ws + SH2, 1.f / 230400.f);
  bnrelupool_kernel<40, 30, 30, 15, 15><<<9000, 256, 0, stream>>>(A, B_, ws + SC2, ws + SH2, 2304000);
  // stage 3
  conv3_kernel<<<dim3(1, 10, 256), 256, 0, stream>>>(B_, c3w, c3b, A, ws + P3S, ws + P3Q);
  bnfin_kernel<256><<<60, 256, 0, stream>>>(ws + P3S, ws + P3Q, g3, b3, ws + SC3, ws + SH3, 1.f / 50176.f);
  bnrelupool_kernel<60, 14, 14, 7, 7><<<2940, 256, 0, stream>>>(A, C_, ws + SC3, ws + SH3, 752640);
  // h -> hT
  transpose_h_kernel<<<dim3(46, 4), 256, 0, stream>>>(C_, B_);
  // locally connected (coalesced): lcT into A
  lc2_kernel<<<dim3(36, 10), 256, 0, stream>>>(B_, lcw, lcb, A, ws + P4S, ws + P4Q);
  bnfin_kernel<36><<<80, 256, 0, stream>>>(ws + P4S, ws + P4Q, g4, b4, ws + SC4, ws + SH4, 1.f / 9216.f);
  lcpost2_kernel<<<dim3(45, 4), 256, 0, stream>>>(A, D_, ws + SC4, ws + SH4);
  // fc via bf16 MFMA (fc_b cancels under BN1d); A region is free now
  pack_feat_kernel<<<1536, 256, 0, stream>>>(C_, D_, featB);
  pack_w_kernel<<<4608, 256, 0, stream>>>(fcw, WB);
  fc_mfma_kernel<<<dim3(4, 12, 4), 256, 0, stream>>>(featB, WB, Y);
  bn5_stats_kernel<<<12, 256, 0, stream>>>(Y, g5, b5, ws + SC5, ws + SH5);
  final_kernel<<<48, 256, 0, stream>>>(Y, ws + SC5, ws + SH5, fw, fb, (float*)d_out);
}

// Round 8
// 361.969 us; speedup vs baseline: 2.4684x; 1.1395x over previous
//
#include <hip/hip_runtime.h>

#define EPSF 1e-5f

// ---------------- workspace layout (float offsets) ----------------
#define P1S 0          // [20][4096]
#define P1Q 81920
#define P2S 163840     // [40][1024]
#define P2Q 204800
#define P3S 245760     // [60][256]
#define P3Q 261120
#define P4S 276480     // [80][36]
#define P4Q 279360
#define SC1 282240
#define SH1 282260
#define SC2 282280
#define SH2 282320
#define SC3 282360
#define SH3 282420
#define SC4 282480
#define SH4 282560
#define SC5 282640     // [768]
#define SH5 283408

#define OFF_A 524288            // pool2 / lcT / featB+WB (19.6M cap)
#define OFF_B 20205568          // pool1 / conv3raw / hT (4.9M cap)
#define OFF_C 25125888          // h (x1): 752,640
#define OFF_D 25878528          // x2: 737,280
#define OFF_Y 26615808          // y: 196,608

#define KP 6144                 // padded K for bf16 GEMM

// ---------------- helpers ----------------
__device__ __forceinline__ void blockReduce2(float& v1, float& v2) {
  __syncthreads();
  #pragma unroll
  for (int off = 32; off > 0; off >>= 1) {
    v1 += __shfl_down(v1, off);
    v2 += __shfl_down(v2, off);
  }
  __shared__ float s1[4], s2[4];
  const int wid = threadIdx.x >> 6, lane = threadIdx.x & 63;
  if (lane == 0) { s1[wid] = v1; s2[wid] = v2; }
  __syncthreads();
  if (threadIdx.x == 0) { v1 = s1[0]+s1[1]+s1[2]+s1[3]; v2 = s2[0]+s2[1]+s2[2]+s2[3]; }
}

__device__ __forceinline__ void waveReduce2(float& a, float& b) {
  #pragma unroll
  for (int off = 32; off > 0; off >>= 1) {
    a += __shfl_down(a, off);
    b += __shfl_down(b, off);
  }
}

__device__ __forceinline__ unsigned short f2bf(float f) {
  unsigned int u = __float_as_uint(f);
  return (unsigned short)((u + 0x7FFFu + ((u >> 16) & 1u)) >> 16);
}

// ---------------- conv1 stats v2: pool-window layout, wave-reduce only ----------
__global__ __launch_bounds__(256) void conv1_stats_kernel(
    const float* __restrict__ x, const float* __restrict__ w, const float* __restrict__ cb,
    float* __restrict__ ps, float* __restrict__ pq) {
  const int sp = blockIdx.x * 256 + threadIdx.x;  // pooled pixel, 961
  const int c0 = blockIdx.y * 5, b = blockIdx.z;
  __shared__ float wsh[5][27];
  if (threadIdx.x < 135) wsh[threadIdx.x / 27][threadIdx.x % 27] = w[c0 * 27 + threadIdx.x];
  __syncthreads();
  float s[5] = {}, q[5] = {};
  if (sp < 961) {
    const int py = sp / 31, px = sp - py * 31;
    const float* xb = x + (size_t)b * 3 * 4096 + (2 * py) * 64 + 2 * px;
    float acc[5][4] = {};
    #pragma unroll
    for (int ic = 0; ic < 3; ic++) {
      float v[4][4];
      #pragma unroll
      for (int r = 0; r < 4; r++)
        #pragma unroll
        for (int cc = 0; cc < 4; cc++)
          v[r][cc] = xb[ic * 4096 + r * 64 + cc];
      #pragma unroll
      for (int ol = 0; ol < 5; ol++)
        #pragma unroll
        for (int dy = 0; dy < 2; dy++)
          #pragma unroll
          for (int dx = 0; dx < 2; dx++) {
            float a = acc[ol][dy * 2 + dx];
            #pragma unroll
            for (int ky = 0; ky < 3; ky++)
              #pragma unroll
              for (int kx = 0; kx < 3; kx++)
                a = fmaf(v[dy + ky][dx + kx], wsh[ol][(ic * 3 + ky) * 3 + kx], a);
            acc[ol][dy * 2 + dx] = a;
          }
    }
    #pragma unroll
    for (int ol = 0; ol < 5; ol++) {
      const float base = cb[c0 + ol];
      #pragma unroll
      for (int k = 0; k < 4; k++) {
        const float vv = acc[ol][k] + base;
        s[ol] += vv; q[ol] += vv * vv;
      }
    }
  }
  #pragma unroll
  for (int ol = 0; ol < 5; ol++) waveReduce2(s[ol], q[ol]);
  const int lane = threadIdx.x & 63, wid = threadIdx.x >> 6;
  if (lane == 0) {
    const int slot = b * 16 + blockIdx.x * 4 + wid;
    #pragma unroll
    for (int ol = 0; ol < 5; ol++) {
      ps[(c0 + ol) * 4096 + slot] = s[ol];
      pq[(c0 + ol) * 4096 + slot] = q[ol];
    }
  }
}

// ---------------- fused conv1 + BN + ReLU + pool (recompute) ----------------
__global__ __launch_bounds__(256) void convpool1_kernel(
    const float* __restrict__ x, const float* __restrict__ w, const float* __restrict__ cb,
    const float* __restrict__ scale, const float* __restrict__ shift,
    float* __restrict__ out) {
  const int sp = blockIdx.x * 256 + threadIdx.x;  // pooled pixel, 961
  const int c0 = blockIdx.y * 5, b = blockIdx.z;
  __shared__ float wsh[5][27];
  if (threadIdx.x < 135) wsh[threadIdx.x / 27][threadIdx.x % 27] = w[c0 * 27 + threadIdx.x];
  __syncthreads();
  if (sp >= 961) return;
  const int py = sp / 31, px = sp - py * 31;
  const float* xb = x + (size_t)b * 3 * 4096 + (2 * py) * 64 + 2 * px;
  float acc[5][4] = {};
  #pragma unroll
  for (int ic = 0; ic < 3; ic++) {
    float v[4][4];
    #pragma unroll
    for (int r = 0; r < 4; r++)
      #pragma unroll
      for (int cc = 0; cc < 4; cc++)
        v[r][cc] = xb[ic * 4096 + r * 64 + cc];
    #pragma unroll
    for (int ol = 0; ol < 5; ol++)
      #pragma unroll
      for (int dy = 0; dy < 2; dy++)
        #pragma unroll
        for (int dx = 0; dx < 2; dx++) {
          float a = acc[ol][dy * 2 + dx];
          #pragma unroll
          for (int ky = 0; ky < 3; ky++)
            #pragma unroll
            for (int kx = 0; kx < 3; kx++)
              a = fmaf(v[dy + ky][dx + kx], wsh[ol][(ic * 3 + ky) * 3 + kx], a);
          acc[ol][dy * 2 + dx] = a;
        }
  }
  #pragma unroll
  for (int ol = 0; ol < 5; ol++) {
    const float sc = scale[c0 + ol];
    const float sh = fmaf(cb[c0 + ol], sc, shift[c0 + ol]);
    float m = -1e30f;
    #pragma unroll
    for (int k = 0; k < 4; k++)
      m = fmaxf(m, fmaxf(fmaf(acc[ol][k], sc, sh), 0.f));
    out[(size_t)(b * 20 + c0 + ol) * 961 + sp] = m;
  }
}

// ---------------- conv2 stats: pool-window layout, wave-reduce ----------------
__global__ __launch_bounds__(256) void conv2_stats_kernel(
    const float* __restrict__ in, const float* __restrict__ w, const float* __restrict__ cb,
    float* __restrict__ ps, float* __restrict__ pq) {
  const int sp = threadIdx.x;  // pooled pixel, 225
  const int c0 = blockIdx.y * 8, b = blockIdx.z;
  __shared__ float4 wsh4[8][20];
  for (int e = threadIdx.x; e < 160; e += 256)
    wsh4[e / 20][e % 20] = ((const float4*)w)[c0 * 20 + e];
  __syncthreads();
  float s[8] = {}, q[8] = {};
  if (sp < 225) {
    const int py = sp / 15, px = sp - py * 15;
    const float* ib = in + (size_t)b * 20 * 961 + (2 * py) * 31 + 2 * px;
    float acc[8][4] = {};
    #pragma unroll 4
    for (int ic = 0; ic < 20; ic++) {
      float v[3][3];
      #pragma unroll
      for (int r = 0; r < 3; r++)
        #pragma unroll
        for (int cc = 0; cc < 3; cc++)
          v[r][cc] = ib[ic * 961 + r * 31 + cc];
      #pragma unroll
      for (int ol = 0; ol < 8; ol++) {
        const float4 wv = wsh4[ol][ic];
        #pragma unroll
        for (int dy = 0; dy < 2; dy++)
          #pragma unroll
          for (int dx = 0; dx < 2; dx++) {
            float a = acc[ol][dy * 2 + dx];
            a = fmaf(v[dy][dx],     wv.x, a);
            a = fmaf(v[dy][dx + 1], wv.y, a);
            a = fmaf(v[dy + 1][dx], wv.z, a);
            a = fmaf(v[dy + 1][dx + 1], wv.w, a);
            acc[ol][dy * 2 + dx] = a;
          }
      }
    }
    #pragma unroll
    for (int ol = 0; ol < 8; ol++) {
      const float base = cb[c0 + ol];
      #pragma unroll
      for (int k = 0; k < 4; k++) {
        const float vv = acc[ol][k] + base;
        s[ol] += vv; q[ol] += vv * vv;
      }
    }
  }
  #pragma unroll
  for (int ol = 0; ol < 8; ol++) waveReduce2(s[ol], q[ol]);
  const int lane = threadIdx.x & 63, wid = threadIdx.x >> 6;
  if (lane == 0) {
    const int slot = b * 4 + wid;
    #pragma unroll
    for (int ol = 0; ol < 8; ol++) {
      ps[(c0 + ol) * 1024 + slot] = s[ol];
      pq[(c0 + ol) * 1024 + slot] = q[ol];
    }
  }
}

// ---------------- fused conv2 + BN + ReLU + pool (recompute) ----------------
__global__ __launch_bounds__(256) void convpool2_kernel(
    const float* __restrict__ in, const float* __restrict__ w, const float* __restrict__ cb,
    const float* __restrict__ scale, const float* __restrict__ shift,
    float* __restrict__ out) {
  const int sp = threadIdx.x;  // 225
  const int c0 = blockIdx.y * 8, b = blockIdx.z;
  __shared__ float4 wsh4[8][20];
  for (int e = threadIdx.x; e < 160; e += 256)
    wsh4[e / 20][e % 20] = ((const float4*)w)[c0 * 20 + e];
  __syncthreads();
  if (sp >= 225) return;
  const int py = sp / 15, px = sp - py * 15;
  const float* ib = in + (size_t)b * 20 * 961 + (2 * py) * 31 + 2 * px;
  float acc[8][4] = {};
  #pragma unroll 4
  for (int ic = 0; ic < 20; ic++) {
    float v[3][3];
    #pragma unroll
    for (int r = 0; r < 3; r++)
      #pragma unroll
      for (int cc = 0; cc < 3; cc++)
        v[r][cc] = ib[ic * 961 + r * 31 + cc];
    #pragma unroll
    for (int ol = 0; ol < 8; ol++) {
      const float4 wv = wsh4[ol][ic];
      #pragma unroll
      for (int dy = 0; dy < 2; dy++)
        #pragma unroll
        for (int dx = 0; dx < 2; dx++) {
          float a = acc[ol][dy * 2 + dx];
          a = fmaf(v[dy][dx],     wv.x, a);
          a = fmaf(v[dy][dx + 1], wv.y, a);
          a = fmaf(v[dy + 1][dx], wv.z, a);
          a = fmaf(v[dy + 1][dx + 1], wv.w, a);
          acc[ol][dy * 2 + dx] = a;
        }
    }
  }
  #pragma unroll
  for (int ol = 0; ol < 8; ol++) {
    const float sc = scale[c0 + ol];
    const float sh = fmaf(cb[c0 + ol], sc, shift[c0 + ol]);
    float m = -1e30f;
    #pragma unroll
    for (int k = 0; k < 4; k++)
      m = fmaxf(m, fmaxf(fmaf(acc[ol][k], sc, sh), 0.f));
    out[(size_t)(b * 40 + c0 + ol) * 225 + sp] = m;
  }
}

// ---------------- conv3: 2x2, ic=40, 60 oc, OCB=6 ----------------
__global__ __launch_bounds__(256) void conv3_kernel(
    const float* __restrict__ in, const float* __restrict__ w, const float* __restrict__ cb,
    float* __restrict__ out, float* __restrict__ ps, float* __restrict__ pq) {
  const int sp = threadIdx.x;
  const int c0 = blockIdx.y * 6, b = blockIdx.z;
  __shared__ float4 wsh4[6][40];   // [ol][ic]
  if (threadIdx.x < 240)
    wsh4[threadIdx.x / 40][threadIdx.x % 40] = ((const float4*)w)[c0 * 40 + threadIdx.x];
  __syncthreads();
  float acc[6] = {};
  if (sp < 196) {
    const int oy = sp / 14, ox = sp - oy * 14;
    const float* ib = in + (size_t)b * 40 * 225 + oy * 15 + ox;
    #pragma unroll 4
    for (int ic = 0; ic < 40; ic++) {
      const float v0 = ib[ic * 225];
      const float v1 = ib[ic * 225 + 1];
      const float v2 = ib[ic * 225 + 15];
      const float v3 = ib[ic * 225 + 16];
      #pragma unroll
      for (int ol = 0; ol < 6; ol++) {
        const float4 wv = wsh4[ol][ic];
        acc[ol] = fmaf(v0, wv.x, acc[ol]);
        acc[ol] = fmaf(v1, wv.y, acc[ol]);
        acc[ol] = fmaf(v2, wv.z, acc[ol]);
        acc[ol] = fmaf(v3, wv.w, acc[ol]);
      }
    }
    #pragma unroll
    for (int ol = 0; ol < 6; ol++) {
      acc[ol] += cb[c0 + ol];
      out[(size_t)(b * 60 + c0 + ol) * 196 + sp] = acc[ol];
    }
  }
  #pragma unroll
  for (int ol = 0; ol < 6; ol++) {
    float v1 = acc[ol], v2 = acc[ol] * acc[ol];
    blockReduce2(v1, v2);
    if (threadIdx.x == 0) {
      ps[(c0 + ol) * 256 + b] = v1;
      pq[(c0 + ol) * 256 + b] = v2;
    }
  }
}

// ---------------- BN finalize: partials -> scale/shift ----------------
template<int SLOTS>
__global__ __launch_bounds__(256) void bnfin_kernel(
    const float* __restrict__ ps, const float* __restrict__ pq,
    const float* __restrict__ g, const float* __restrict__ bet,
    float* __restrict__ scale, float* __restrict__ shift, float invN) {
  const int c = blockIdx.x;
  float s = 0.f, q = 0.f;
  for (int i = threadIdx.x; i < SLOTS; i += 256) { s += ps[c * SLOTS + i]; q += pq[c * SLOTS + i]; }
  blockReduce2(s, q);
  if (threadIdx.x == 0) {
    const float m = s * invN;
    const float var = q * invN - m * m;
    const float sc = g[c] * rsqrtf(var + EPSF);
    scale[c] = sc;
    shift[c] = bet[c] - m * sc;
  }
}

// ---------------- fused BN + ReLU + 2x2 maxpool (float2 loads) ----------------
template<int C, int Hin, int Win, int Hout, int Wout>
__global__ __launch_bounds__(256) void bnrelupool_kernel(
    const float* __restrict__ in, float* __restrict__ out,
    const float* __restrict__ scale, const float* __restrict__ shift, int total) {
  const int idx = blockIdx.x * 256 + threadIdx.x;
  if (idx >= total) return;
  const int px = idx % Wout;
  int t = idx / Wout;
  const int py = t % Hout; t /= Hout;
  const int c = t % C;
  const int b = t / C;
  const float sc = scale[c], sh = shift[c];
  const float* p = in + ((size_t)(b * C + c) * Hin + 2 * py) * Win + 2 * px;
  const float2 r0 = *(const float2*)p;
  const float2 r1 = *(const float2*)(p + Win);
  float a0 = fmaxf(fmaf(r0.x, sc, sh), 0.f);
  float a1 = fmaxf(fmaf(r0.y, sc, sh), 0.f);
  float a2 = fmaxf(fmaf(r1.x, sc, sh), 0.f);
  float a3 = fmaxf(fmaf(r1.y, sc, sh), 0.f);
  out[idx] = fmaxf(fmaxf(a0, a1), fmaxf(a2, a3));
}

// ---------------- transpose h [256][2940] -> hT [2940][256] ----------------
__global__ __launch_bounds__(256) void transpose_h_kernel(
    const float* __restrict__ in, float* __restrict__ out) {
  __shared__ float tile[64][65];
  const int lx = threadIdx.x & 63, ly = threadIdx.x >> 6;
  const int c0 = blockIdx.x * 64;   // cp dim (2940)
  const int r0 = blockIdx.y * 64;   // b dim (256)
  #pragma unroll
  for (int i = 0; i < 16; i++) {
    const int b = r0 + ly + i * 4;
    const int cp = c0 + lx;
    tile[ly + i * 4][lx] = (cp < 2940) ? in[(size_t)b * 2940 + cp] : 0.f;
  }
  __syncthreads();
  #pragma unroll
  for (int i = 0; i < 16; i++) {
    const int cp = c0 + ly + i * 4;
    if (cp < 2940) out[(size_t)cp * 256 + r0 + lx] = tile[lx][ly + i * 4];
  }
}

// ---------------- LocallyConnected2d (coalesced, o-tiled) ----------------
__global__ __launch_bounds__(256) void lc2_kernel(
    const float* __restrict__ hT, const float* __restrict__ w, const float* __restrict__ lb,
    float* __restrict__ outT, float* __restrict__ ps, float* __restrict__ pq) {
  const int sp = blockIdx.x;
  const int o0 = blockIdx.y * 8;
  const int b = threadIdx.x;
  __shared__ float wsh[8 * 240];
  for (int e = threadIdx.x; e < 1920; e += 256) {
    const int ol = e / 240, ck = e - ol * 240;
    const int c = ck >> 2, k = ck & 3;
    wsh[e] = w[((size_t)((o0 + ol) * 60 + c) * 36 + sp) * 4 + k];
  }
  __syncthreads();
  const int i = sp / 6, j = sp - i * 6;
  const int pos0 = i * 7 + j;
  float acc[8] = {};
  #pragma unroll 4
  for (int c = 0; c < 60; c++) {
    const float h0 = hT[(size_t)(c * 49 + pos0) * 256 + b];
    const float h1 = hT[(size_t)(c * 49 + pos0 + 1) * 256 + b];
    const float h2 = hT[(size_t)(c * 49 + pos0 + 7) * 256 + b];
    const float h3 = hT[(size_t)(c * 49 + pos0 + 8) * 256 + b];
    #pragma unroll
    for (int ol = 0; ol < 8; ol++) {
      const float* wp = &wsh[ol * 240 + c * 4];
      acc[ol] = fmaf(h0, wp[0], acc[ol]);
      acc[ol] = fmaf(h1, wp[1], acc[ol]);
      acc[ol] = fmaf(h2, wp[2], acc[ol]);
      acc[ol] = fmaf(h3, wp[3], acc[ol]);
    }
  }
  #pragma unroll
  for (int ol = 0; ol < 8; ol++) {
    const int o = o0 + ol;
    const float val = acc[ol] + lb[o * 36 + sp];
    outT[(size_t)(o * 36 + sp) * 256 + b] = val;
    float v1 = val, v2 = val * val;
    blockReduce2(v1, v2);
    if (threadIdx.x == 0) { ps[o * 36 + sp] = v1; pq[o * 36 + sp] = v2; }
  }
}

// ---------------- lcpost: BN+ReLU + transpose lcT [2880][256] -> x2 [256][2880] ----
__global__ __launch_bounds__(256) void lcpost2_kernel(
    const float* __restrict__ inT, float* __restrict__ out,
    const float* __restrict__ scale, const float* __restrict__ shift) {
  __shared__ float tile[64][65];
  const int lx = threadIdx.x & 63, ly = threadIdx.x >> 6;
  const int k0 = blockIdx.x * 64;   // k dim (2880)
  const int b0 = blockIdx.y * 64;   // b dim (256)
  #pragma unroll
  for (int i = 0; i < 16; i++) {
    const int k = k0 + ly + i * 4;
    const int o = k / 36;
    const float v = inT[(size_t)k * 256 + b0 + lx];
    tile[ly + i * 4][lx] = fmaxf(fmaf(v, scale[o], shift[o]), 0.f);
  }
  __syncthreads();
  #pragma unroll
  for (int i = 0; i < 16; i++) {
    const int b = b0 + ly + i * 4;
    out[(size_t)b * 2880 + k0 + lx] = tile[lx][ly + i * 4];
  }
}

// ---------------- pack feat [256][KP] bf16 from h(2940) + x2(2880), zero tail ----
__global__ __launch_bounds__(256) void pack_feat_kernel(
    const float* __restrict__ h, const float* __restrict__ x2, unsigned short* __restrict__ fB) {
  const int idx = blockIdx.x * 256 + threadIdx.x;  // 256*1536 exact
  const int b = idx / 1536, kq = idx - b * 1536;
  const int k0 = kq * 4;
  ushort4 o;
  float v[4];
  #pragma unroll
  for (int q = 0; q < 4; q++) {
    const int k = k0 + q;
    v[q] = (k < 2940) ? h[(size_t)b * 2940 + k]
         : (k < 5820) ? x2[(size_t)b * 2880 + (k - 2940)] : 0.f;
  }
  o.x = f2bf(v[0]); o.y = f2bf(v[1]); o.z = f2bf(v[2]); o.w = f2bf(v[3]);
  *(ushort4*)&fB[(size_t)b * KP + k0] = o;
}

// ---------------- pack W [768][KP] bf16 from fcw [768][5820], zero tail --------
__global__ __launch_bounds__(256) void pack_w_kernel(
    const float* __restrict__ W, unsigned short* __restrict__ WBp) {
  const int idx = blockIdx.x * 256 + threadIdx.x;  // 768*1536 exact
  const int n = idx / 1536, kq = idx - n * 1536;
  const int k0 = kq * 4;
  ushort4 o;
  float v[4];
  #pragma unroll
  for (int q = 0; q < 4; q++) {
    const int k = k0 + q;
    v[q] = (k < 5820) ? W[(size_t)n * 5820 + k] : 0.f;
  }
  o.x = f2bf(v[0]); o.y = f2bf(v[1]); o.z = f2bf(v[2]); o.w = f2bf(v[3]);
  *(ushort4*)&WBp[(size_t)n * KP + k0] = o;
}

// ---------------- FC GEMM via bf16 MFMA: 64x64 tiles, split-K=4, atomics -------
typedef __attribute__((ext_vector_type(4))) float f32x4;
typedef __attribute__((ext_vector_type(8))) short bf16x8;

__global__ __launch_bounds__(256) void fc_mfma_kernel(
    const unsigned short* __restrict__ fB, const unsigned short* __restrict__ WBp,
    float* __restrict__ Y) {
  const int wid = threadIdx.x >> 6, l = threadIdx.x & 63;
  const int wy = wid >> 1, wx = wid & 1;
  const int m0 = blockIdx.x * 64 + wy * 32;
  const int n0 = blockIdx.y * 64 + wx * 32;
  const int lrow = l & 15, lk = (l >> 4) * 8;
  const unsigned short* ap = fB + (size_t)(m0 + lrow) * KP + lk;
  const unsigned short* bp = WBp + (size_t)(n0 + lrow) * KP + lk;
  f32x4 acc[2][2] = {};
  const int kbase = blockIdx.z * 1536;
  #pragma unroll 4
  for (int s = 0; s < 48; s++) {
    const int k = kbase + s * 32;
    const bf16x8 a0 = *(const bf16x8*)(ap + k);
    const bf16x8 a1 = *(const bf16x8*)(ap + 16 * KP + k);
    const bf16x8 b0 = *(const bf16x8*)(bp + k);
    const bf16x8 b1 = *(const bf16x8*)(bp + 16 * KP + k);
    acc[0][0] = __builtin_amdgcn_mfma_f32_16x16x32_bf16(a0, b0, acc[0][0], 0, 0, 0);
    acc[0][1] = __builtin_amdgcn_mfma_f32_16x16x32_bf16(a0, b1, acc[0][1], 0, 0, 0);
    acc[1][0] = __builtin_amdgcn_mfma_f32_16x16x32_bf16(a1, b0, acc[1][0], 0, 0, 0);
    acc[1][1] = __builtin_amdgcn_mfma_f32_16x16x32_bf16(a1, b1, acc[1][1], 0, 0, 0);
  }
  const int orow = (l >> 4) * 4, ocol = l & 15;
  #pragma unroll
  for (int fi = 0; fi < 2; fi++)
    #pragma unroll
    for (int fj = 0; fj < 2; fj++)
      #pragma unroll
      for (int r = 0; r < 4; r++)
        atomicAdd(&Y[(size_t)(m0 + fi * 16 + orow + r) * 768 + n0 + fj * 16 + ocol],
                  acc[fi][fj][r]);
}

// ---------------- BN5 stats (per-feature over batch), coalesced ----------------
__global__ __launch_bounds__(256) void bn5_stats_kernel(
    const float* __restrict__ Y, const float* __restrict__ g, const float* __restrict__ bet,
    float* __restrict__ scale, float* __restrict__ shift) {
  const int tx = threadIdx.x & 63, ty = threadIdx.x >> 6;
  const int n = blockIdx.x * 64 + tx;
  float s = 0.f, q = 0.f;
  for (int bi = 0; bi < 64; bi++) {
    const float v = Y[(size_t)(bi * 4 + ty) * 768 + n];
    s += v; q += v * v;
  }
  __shared__ float rs[4][64], rq[4][64];
  rs[ty][tx] = s; rq[ty][tx] = q;
  __syncthreads();
  if (ty == 0) {
    s = rs[0][tx] + rs[1][tx] + rs[2][tx] + rs[3][tx];
    q = rq[0][tx] + rq[1][tx] + rq[2][tx] + rq[3][tx];
    const float m = s * (1.f / 256.f);
    const float var = q * (1.f / 256.f) - m * m;
    const float sc = g[n] * rsqrtf(var + EPSF);
    scale[n] = sc;
    shift[n] = bet[n] - m * sc;
  }
}

// ---------------- final fuse ----------------
__global__ __launch_bounds__(256) void final_kernel(
    const float* __restrict__ Y, const float* __restrict__ scale, const float* __restrict__ shift,
    const float* __restrict__ fw, const float* __restrict__ fb, float* __restrict__ out) {
  const int idx = blockIdx.x * 256 + threadIdx.x;  // 12288 exact
  const int b = idx / 48, hh = idx - b * 48;
  const float* yb = Y + (size_t)b * 768 + hh * 16;
  const float* sc = scale + hh * 16;
  const float* sh = shift + hh * 16;
  const float* w = fw + hh * 16;
  float acc = fb[hh];
  #pragma unroll
  for (int s = 0; s < 16; s++)
    acc += fmaxf(fmaf(yb[s], sc[s], sh[s]), 0.f) * w[s];
  out[idx] = acc;
}

// ---------------- launch ----------------
extern "C" void kernel_launch(void* const* d_in, const int* in_sizes, int n_in,
                              void* d_out, int out_size, void* d_ws, size_t ws_size,
                              hipStream_t stream) {
  const float* x   = (const float*)d_in[0];
  const float* c1w = (const float*)d_in[1];
  const float* c1b = (const float*)d_in[2];
  const float* g1  = (const float*)d_in[3];
  const float* b1  = (const float*)d_in[4];
  const float* c2w = (const float*)d_in[5];
  const float* c2b = (const float*)d_in[6];
  const float* g2  = (const float*)d_in[7];
  const float* b2  = (const float*)d_in[8];
  const float* c3w = (const float*)d_in[9];
  const float* c3b = (const float*)d_in[10];
  const float* g3  = (const float*)d_in[11];
  const float* b3  = (const float*)d_in[12];
  const float* lcw = (const float*)d_in[13];
  const float* lcb = (const float*)d_in[14];
  const float* g4  = (const float*)d_in[15];
  const float* b4  = (const float*)d_in[16];
  const float* fcw = (const float*)d_in[17];
  const float* g5  = (const float*)d_in[19];
  const float* b5  = (const float*)d_in[20];
  const float* fw  = (const float*)d_in[21];
  const float* fb  = (const float*)d_in[22];

  float* ws = (float*)d_ws;
  float* A  = ws + OFF_A;   // pool2 / lcT / featB+WB
  float* B_ = ws + OFF_B;   // pool1 / conv3raw / hT
  float* C_ = ws + OFF_C;   // h (x1)
  float* D_ = ws + OFF_D;   // x2
  float* Y  = ws + OFF_Y;
  unsigned short* featB = (unsigned short*)A;                 // 256*KP bf16 = 786432 floats
  unsigned short* WB    = (unsigned short*)(A + 786432);

  hipMemsetAsync(Y, 0, 196608 * sizeof(float), stream);

  // stage 1: stats (pool-window, wave-reduce) -> finalize -> fused conv+BN+ReLU+pool
  conv1_stats_kernel<<<dim3(4, 4, 256), 256, 0, stream>>>(x, c1w, c1b, ws + P1S, ws + P1Q);
  bnfin_kernel<4096><<<20, 256, 0, stream>>>(ws + P1S, ws + P1Q, g1, b1, ws + SC1, ws + SH1, 1.f / 984064.f);
  convpool1_kernel<<<dim3(4, 4, 256), 256, 0, stream>>>(x, c1w, c1b, ws + SC1, ws + SH1, B_);
  // stage 2: stats (no raw store) -> finalize -> fused conv+BN+ReLU+pool
  conv2_stats_kernel<<<dim3(1, 5, 256), 256, 0, stream>>>(B_, c2w, c2b, ws + P2S, ws + P2Q);
  bnfin_kernel<1024><<<40, 256, 0, stream>>>(ws + P2S, ws + P2Q, g2, b2, ws + SC2, ws + SH2, 1.f / 230400.f);
  convpool2_kernel<<<dim3(1, 5, 256), 256, 0, stream>>>(B_, c2w, c2b, ws + SC2, ws + SH2, A);
  // stage 3: conv3 raw into B_ (pool1 dead), pool into C_
  conv3_kernel<<<dim3(1, 10, 256), 256, 0, stream>>>(A, c3w, c3b, B_, ws + P3S, ws + P3Q);
  bnfin_kernel<256><<<60, 256, 0, stream>>>(ws + P3S, ws + P3Q, g3, b3, ws + SC3, ws + SH3, 1.f / 50176.f);
  bnrelupool_kernel<60, 14, 14, 7, 7><<<2940, 256, 0, stream>>>(B_, C_, ws + SC3, ws + SH3, 752640);
  // h -> hT (B_ free after bnrelupool3)
  transpose_h_kernel<<<dim3(46, 4), 256, 0, stream>>>(C_, B_);
  // locally connected (coalesced): lcT into A (pool2 dead)
  lc2_kernel<<<dim3(36, 10), 256, 0, stream>>>(B_, lcw, lcb, A, ws + P4S, ws + P4Q);
  bnfin_kernel<36><<<80, 256, 0, stream>>>(ws + P4S, ws + P4Q, g4, b4, ws + SC4, ws + SH4, 1.f / 9216.f);
  lcpost2_kernel<<<dim3(45, 4), 256, 0, stream>>>(A, D_, ws + SC4, ws + SH4);
  // fc via bf16 MFMA (fc_b cancels under BN1d); A region free after lcpost2
  pack_feat_kernel<<<1536, 256, 0, stream>>>(C_, D_, featB);
  pack_w_kernel<<<4608, 256, 0, stream>>>(fcw, WB);
  fc_mfma_kernel<<<dim3(4, 12, 4), 256, 0, stream>>>(featB, WB, Y);
  bn5_stats_kernel<<<12, 256, 0, stream>>>(Y, g5, b5, ws + SC5, ws + SH5);
  final_kernel<<<48, 256, 0, stream>>>(Y, ws + SC5, ws + SH5, fw, fb, (float*)d_out);
}